// Round 1
// baseline (751.978 us; speedup 1.0000x reference)
//
#include <hip/hip_runtime.h>

#define N_NODES 50000
#define N_EDGES 800000
#define HID 128
#define OUTC 10
#define N_GRAPHS 64
#define BN_EPS 1e-5f

#define SCAN_CHUNK 1024
#define NCHUNKS ((N_NODES + SCAN_CHUNK - 1) / SCAN_CHUNK)   // 49

// ---------------- CSR build ----------------
__global__ void k_count(const int* __restrict__ dst, int* __restrict__ deg) {
    int e = blockIdx.x * 256 + threadIdx.x;
    if (e < N_EDGES) atomicAdd(&deg[dst[e]], 1);
}

__global__ void k_scan1(const int* __restrict__ deg, int* __restrict__ chunkSums) {
    __shared__ int sh[256];
    int base = blockIdx.x * SCAN_CHUNK;
    int t = threadIdx.x;
    int s = 0;
#pragma unroll
    for (int i = 0; i < 4; i++) {
        int idx = base + t * 4 + i;
        if (idx < N_NODES) s += deg[idx];
    }
    sh[t] = s;
    __syncthreads();
    for (int off = 128; off > 0; off >>= 1) {
        if (t < off) sh[t] += sh[t + off];
        __syncthreads();
    }
    if (t == 0) chunkSums[blockIdx.x] = sh[0];
}

__global__ void k_scan2(int* chunkSums, int* offs) {
    if (threadIdx.x == 0) {
        int run = 0;
        for (int i = 0; i < NCHUNKS; i++) {
            int v = chunkSums[i];
            chunkSums[i] = run;
            run += v;
        }
        offs[N_NODES] = run;   // == N_EDGES
    }
}

__global__ void k_scan3(const int* __restrict__ deg, const int* __restrict__ chunkSums,
                        int* __restrict__ offs) {
    __shared__ int sh[256];
    int base = blockIdx.x * SCAN_CHUNK;
    int t = threadIdx.x;
    int v[4];
    int s = 0;
#pragma unroll
    for (int i = 0; i < 4; i++) {
        int idx = base + t * 4 + i;
        v[i] = (idx < N_NODES) ? deg[idx] : 0;
        s += v[i];
    }
    sh[t] = s;
    __syncthreads();
    // Hillis-Steele inclusive scan over 256 thread sums
    for (int off = 1; off < 256; off <<= 1) {
        int x = sh[t];
        if (t >= off) x += sh[t - off];
        __syncthreads();
        sh[t] = x;
        __syncthreads();
    }
    int excl = sh[t] - s;
    int run = chunkSums[blockIdx.x] + excl;
#pragma unroll
    for (int i = 0; i < 4; i++) {
        int idx = base + t * 4 + i;
        if (idx < N_NODES) offs[idx] = run;
        run += v[i];
    }
}

__global__ void k_fill(const int* __restrict__ src, const int* __restrict__ dst,
                       const int* __restrict__ offs, int* __restrict__ cursor,
                       int* __restrict__ srcSorted) {
    int e = blockIdx.x * 256 + threadIdx.x;
    if (e < N_EDGES) {
        int d = dst[e];
        int pos = offs[d] + atomicAdd(&cursor[d], 1);
        srcSorted[pos] = src[e];
    }
}

// ---------------- Aggregation: h0 = x + sum_{j->i} x_j ----------------
__global__ void k_agg(const float* __restrict__ x, const int* __restrict__ offs,
                      const int* __restrict__ srcSorted, float* __restrict__ h0) {
    int node = blockIdx.x * 8 + (threadIdx.x >> 5);
    int lane = threadIdx.x & 31;
    if (node >= N_NODES) return;
    int c = lane * 4;
    float4 acc = *(const float4*)&x[(size_t)node * HID + c];
    int e0 = offs[node], e1 = offs[node + 1];
    for (int e = e0; e < e1; e++) {
        int s = srcSorted[e];
        float4 v = *(const float4*)&x[(size_t)s * HID + c];
        acc.x += v.x; acc.y += v.y; acc.z += v.z; acc.w += v.w;
    }
    *(float4*)&h0[(size_t)node * HID + c] = acc;
}

// ---------------- Fused MLP: h = relu(h0 W1 + b1) W2 + b2, + BN partial sums ----------------
#define MROWS 64
#define LDW 132   // 128 + 4 pad

__global__ __launch_bounds__(256) void k_mlp(const float* __restrict__ h0,
                                             const float* __restrict__ W1,
                                             const float* __restrict__ b1,
                                             const float* __restrict__ W2,
                                             const float* __restrict__ b2,
                                             float* __restrict__ h,
                                             float* __restrict__ bnsum) {
    __shared__ float As[MROWS * LDW];
    __shared__ float bnS[HID];
    __shared__ float bnS2[HID];

    int tid = threadIdx.x;
    int rowBase = blockIdx.x * MROWS;

    // load 64x128 tile (zero-pad invalid rows)
#pragma unroll
    for (int i = 0; i < 8; i++) {
        int fid = tid + i * 256;      // 0..2047 float4 slots
        int r = fid >> 5;
        int c4 = (fid & 31) * 4;
        int gr = rowBase + r;
        float4 v = make_float4(0.f, 0.f, 0.f, 0.f);
        if (gr < N_NODES) v = *(const float4*)&h0[(size_t)gr * HID + c4];
        *(float4*)&As[r * LDW + c4] = v;
    }
    if (tid < HID) { bnS[tid] = 0.f; bnS2[tid] = 0.f; }
    __syncthreads();

    int cg = tid & 15, rg = tid >> 4;
    int c0 = cg * 8, r0 = rg * 4;

    float acc[4][8];
#pragma unroll
    for (int i = 0; i < 4; i++)
#pragma unroll
        for (int j = 0; j < 8; j++) acc[i][j] = 0.f;

    // ---- GEMM1: As @ W1 ----
    for (int k = 0; k < HID; k += 4) {
        float a_[4][4];
        *(float4*)&a_[0][0] = *(const float4*)&As[(r0 + 0) * LDW + k];
        *(float4*)&a_[1][0] = *(const float4*)&As[(r0 + 1) * LDW + k];
        *(float4*)&a_[2][0] = *(const float4*)&As[(r0 + 2) * LDW + k];
        *(float4*)&a_[3][0] = *(const float4*)&As[(r0 + 3) * LDW + k];
#pragma unroll
        for (int kk = 0; kk < 4; kk++) {
            float4 wA = *(const float4*)&W1[(k + kk) * HID + c0];
            float4 wB = *(const float4*)&W1[(k + kk) * HID + c0 + 4];
            float w[8] = {wA.x, wA.y, wA.z, wA.w, wB.x, wB.y, wB.z, wB.w};
#pragma unroll
            for (int i = 0; i < 4; i++)
#pragma unroll
                for (int j = 0; j < 8; j++) acc[i][j] += a_[i][kk] * w[j];
        }
    }

    // bias + relu
    {
        float4 bA = *(const float4*)&b1[c0];
        float4 bB = *(const float4*)&b1[c0 + 4];
        float bb[8] = {bA.x, bA.y, bA.z, bA.w, bB.x, bB.y, bB.z, bB.w};
#pragma unroll
        for (int i = 0; i < 4; i++)
#pragma unroll
            for (int j = 0; j < 8; j++) {
                float v = acc[i][j] + bb[j];
                acc[i][j] = v > 0.f ? v : 0.f;
            }
    }

    __syncthreads();
    // write T back into As
#pragma unroll
    for (int i = 0; i < 4; i++) {
        *(float4*)&As[(r0 + i) * LDW + c0]     = make_float4(acc[i][0], acc[i][1], acc[i][2], acc[i][3]);
        *(float4*)&As[(r0 + i) * LDW + c0 + 4] = make_float4(acc[i][4], acc[i][5], acc[i][6], acc[i][7]);
    }
    __syncthreads();

#pragma unroll
    for (int i = 0; i < 4; i++)
#pragma unroll
        for (int j = 0; j < 8; j++) acc[i][j] = 0.f;

    // ---- GEMM2: T @ W2 ----
    for (int k = 0; k < HID; k += 4) {
        float a_[4][4];
        *(float4*)&a_[0][0] = *(const float4*)&As[(r0 + 0) * LDW + k];
        *(float4*)&a_[1][0] = *(const float4*)&As[(r0 + 1) * LDW + k];
        *(float4*)&a_[2][0] = *(const float4*)&As[(r0 + 2) * LDW + k];
        *(float4*)&a_[3][0] = *(const float4*)&As[(r0 + 3) * LDW + k];
#pragma unroll
        for (int kk = 0; kk < 4; kk++) {
            float4 wA = *(const float4*)&W2[(k + kk) * HID + c0];
            float4 wB = *(const float4*)&W2[(k + kk) * HID + c0 + 4];
            float w[8] = {wA.x, wA.y, wA.z, wA.w, wB.x, wB.y, wB.z, wB.w};
#pragma unroll
            for (int i = 0; i < 4; i++)
#pragma unroll
                for (int j = 0; j < 8; j++) acc[i][j] += a_[i][kk] * w[j];
        }
    }

    // bias + store + BN partials
    {
        float4 bA = *(const float4*)&b2[c0];
        float4 bB = *(const float4*)&b2[c0 + 4];
        float bb[8] = {bA.x, bA.y, bA.z, bA.w, bB.x, bB.y, bB.z, bB.w};
        float s1[8], s2v[8];
#pragma unroll
        for (int j = 0; j < 8; j++) { s1[j] = 0.f; s2v[j] = 0.f; }
#pragma unroll
        for (int i = 0; i < 4; i++) {
            int gr = rowBase + r0 + i;
            if (gr < N_NODES) {
                float v0 = acc[i][0] + bb[0], v1 = acc[i][1] + bb[1];
                float v2 = acc[i][2] + bb[2], v3 = acc[i][3] + bb[3];
                float v4 = acc[i][4] + bb[4], v5 = acc[i][5] + bb[5];
                float v6 = acc[i][6] + bb[6], v7 = acc[i][7] + bb[7];
                *(float4*)&h[(size_t)gr * HID + c0]     = make_float4(v0, v1, v2, v3);
                *(float4*)&h[(size_t)gr * HID + c0 + 4] = make_float4(v4, v5, v6, v7);
                s1[0] += v0; s2v[0] += v0 * v0;  s1[1] += v1; s2v[1] += v1 * v1;
                s1[2] += v2; s2v[2] += v2 * v2;  s1[3] += v3; s2v[3] += v3 * v3;
                s1[4] += v4; s2v[4] += v4 * v4;  s1[5] += v5; s2v[5] += v5 * v5;
                s1[6] += v6; s2v[6] += v6 * v6;  s1[7] += v7; s2v[7] += v7 * v7;
            }
        }
#pragma unroll
        for (int j = 0; j < 8; j++) {
            atomicAdd(&bnS[c0 + j], s1[j]);
            atomicAdd(&bnS2[c0 + j], s2v[j]);
        }
    }
    __syncthreads();
    if (tid < HID) {
        atomicAdd(&bnsum[tid], bnS[tid]);
        atomicAdd(&bnsum[HID + tid], bnS2[tid]);
    }
}

// ---------------- BN scale/shift ----------------
__global__ void k_bnscale(const float* __restrict__ bnsum, const float* __restrict__ gamma,
                          const float* __restrict__ beta, float* __restrict__ sc) {
    int c = threadIdx.x;
    if (c < HID) {
        float mean = bnsum[c] * (1.0f / N_NODES);
        float var = bnsum[HID + c] * (1.0f / N_NODES) - mean * mean;
        float s = gamma[c] * rsqrtf(var + BN_EPS);
        sc[c] = s;
        sc[HID + c] = beta[c] - mean * s;
    }
}

// ---------------- BN apply + ReLU ----------------
__global__ void k_bnapply(const float* __restrict__ h, const float* __restrict__ sc,
                          float* __restrict__ xout) {
    int idx = blockIdx.x * 256 + threadIdx.x;   // over N*HID/4
    if (idx >= N_NODES * HID / 4) return;
    int c4 = (idx & 31) * 4;
    float4 v = *(const float4*)&h[(size_t)idx * 4];
    float4 s = *(const float4*)&sc[c4];
    float4 b = *(const float4*)&sc[HID + c4];
    v.x = fmaxf(v.x * s.x + b.x, 0.f);
    v.y = fmaxf(v.y * s.y + b.y, 0.f);
    v.z = fmaxf(v.z * s.z + b.z, 0.f);
    v.w = fmaxf(v.w * s.w + b.w, 0.f);
    *(float4*)&xout[(size_t)idx * 4] = v;
}

// ---------------- Pool (batch sorted -> segmented register accumulation) ----------------
#define POOL_CHUNK 512
__global__ void k_pool(const float* __restrict__ X, const int* __restrict__ batch,
                       float* __restrict__ g) {
    int lane = threadIdx.x & 31;
    int rg = threadIdx.x >> 5;    // 0..7
    int c = lane * 4;
    int base = blockIdx.x * POOL_CHUNK;
    int end = base + POOL_CHUNK;
    if (end > N_NODES) end = N_NODES;
    float4 acc = make_float4(0.f, 0.f, 0.f, 0.f);
    int cur = -1;
    for (int r = base + rg; r < end; r += 8) {
        int b = batch[r];
        if (b != cur) {
            if (cur >= 0) {
                atomicAdd(&g[cur * HID + c + 0], acc.x);
                atomicAdd(&g[cur * HID + c + 1], acc.y);
                atomicAdd(&g[cur * HID + c + 2], acc.z);
                atomicAdd(&g[cur * HID + c + 3], acc.w);
            }
            cur = b;
            acc = make_float4(0.f, 0.f, 0.f, 0.f);
        }
        float4 v = *(const float4*)&X[(size_t)r * HID + c];
        acc.x += v.x; acc.y += v.y; acc.z += v.z; acc.w += v.w;
    }
    if (cur >= 0) {
        atomicAdd(&g[cur * HID + c + 0], acc.x);
        atomicAdd(&g[cur * HID + c + 1], acc.y);
        atomicAdd(&g[cur * HID + c + 2], acc.z);
        atomicAdd(&g[cur * HID + c + 3], acc.w);
    }
}

// ---------------- Final linear ----------------
__global__ void k_final(const float* __restrict__ g, const float* __restrict__ Wlin,
                        const float* __restrict__ blin, float* __restrict__ out) {
    int o = blockIdx.x * 256 + threadIdx.x;
    if (o >= N_GRAPHS * OUTC) return;
    int gi = o / OUTC, c = o % OUTC;
    float s = blin[c];
    for (int k = 0; k < HID; k++) s += g[gi * HID + k] * Wlin[k * OUTC + c];
    out[o] = s;
}

// ---------------- Launch ----------------
extern "C" void kernel_launch(void* const* d_in, const int* in_sizes, int n_in,
                              void* d_out, int out_size, void* d_ws, size_t ws_size,
                              hipStream_t stream) {
    const float* x      = (const float*)d_in[0];
    const float* W1s    = (const float*)d_in[1];
    const float* b1s    = (const float*)d_in[2];
    const float* W2s    = (const float*)d_in[3];
    const float* b2s    = (const float*)d_in[4];
    const float* gammas = (const float*)d_in[5];
    const float* betas  = (const float*)d_in[6];
    const float* Wlin   = (const float*)d_in[7];
    const float* blin   = (const float*)d_in[8];
    const int* edge_index = (const int*)d_in[9];
    const int* batch    = (const int*)d_in[10];
    float* out = (float*)d_out;

    const int* src = edge_index;            // edge_index[0]
    const int* dst = edge_index + N_EDGES;  // edge_index[1]

    // workspace layout (all 16B aligned)
    char* w = (char*)d_ws;
    int* deg       = (int*)w;  w += (size_t)N_NODES * 4;          // 200000
    int* cursor    = (int*)w;  w += (size_t)N_NODES * 4;          // 200000
    int* offs      = (int*)w;  w += 200016;                       // 50001 ints, padded
    int* chunkSums = (int*)w;  w += 256;
    int* srcSorted = (int*)w;  w += (size_t)N_EDGES * 4;          // 3.2 MB
    float* X   = (float*)w;    w += (size_t)N_NODES * HID * 4;    // 25.6 MB
    float* H0  = (float*)w;    w += (size_t)N_NODES * HID * 4;
    float* H   = (float*)w;    w += (size_t)N_NODES * HID * 4;
    float* bnsum = (float*)w;  w += 2 * HID * 4;
    float* bnsc  = (float*)w;  w += 2 * HID * 4;
    float* g     = (float*)w;  w += (size_t)N_GRAPHS * HID * 4;   // 32 KB

    hipMemsetAsync(deg, 0, (size_t)N_NODES * 4, stream);
    hipMemsetAsync(cursor, 0, (size_t)N_NODES * 4, stream);
    hipMemsetAsync(g, 0, (size_t)N_GRAPHS * HID * 4, stream);

    // CSR build
    k_count<<<(N_EDGES + 255) / 256, 256, 0, stream>>>(dst, deg);
    k_scan1<<<NCHUNKS, 256, 0, stream>>>(deg, chunkSums);
    k_scan2<<<1, 64, 0, stream>>>(chunkSums, offs);
    k_scan3<<<NCHUNKS, 256, 0, stream>>>(deg, chunkSums, offs);
    k_fill<<<(N_EDGES + 255) / 256, 256, 0, stream>>>(src, dst, offs, cursor, srcSorted);

    const float* xin = x;
    for (int l = 0; l < 3; l++) {
        k_agg<<<(N_NODES + 7) / 8, 256, 0, stream>>>(xin, offs, srcSorted, H0);
        hipMemsetAsync(bnsum, 0, 2 * HID * 4, stream);
        k_mlp<<<(N_NODES + MROWS - 1) / MROWS, 256, 0, stream>>>(
            H0, W1s + (size_t)l * HID * HID, b1s + (size_t)l * HID,
            W2s + (size_t)l * HID * HID, b2s + (size_t)l * HID, H, bnsum);
        k_bnscale<<<1, 128, 0, stream>>>(bnsum, gammas + (size_t)l * HID,
                                         betas + (size_t)l * HID, bnsc);
        k_bnapply<<<(N_NODES * HID / 4 + 255) / 256, 256, 0, stream>>>(H, bnsc, X);
        xin = X;
    }

    k_pool<<<(N_NODES + POOL_CHUNK - 1) / POOL_CHUNK, 256, 0, stream>>>(X, batch, g);
    k_final<<<(N_GRAPHS * OUTC + 255) / 256, 256, 0, stream>>>(g, Wlin, blin, out);
}

// Round 2
// 562.928 us; speedup vs baseline: 1.3358x; 1.3358x over previous
//
#include <hip/hip_runtime.h>

#define N_NODES 50000
#define N_EDGES 800000
#define HID 128
#define OUTC 10
#define N_GRAPHS 64
#define BN_EPS 1e-5f

#define SCAN_CHUNK 1024
#define NCHUNKS ((N_NODES + SCAN_CHUNK - 1) / SCAN_CHUNK)   // 49

typedef __attribute__((ext_vector_type(8))) short short8_t;
typedef __attribute__((ext_vector_type(4))) float f32x4;

__device__ __forceinline__ unsigned short f2bf(float f) {
    unsigned u = __float_as_uint(f);
    u += 0x7FFFu + ((u >> 16) & 1u);     // RNE
    return (unsigned short)(u >> 16);
}
__device__ __forceinline__ float bf2f(unsigned short s) {
    return __uint_as_float(((unsigned)s) << 16);
}

// ---------------- CSR build ----------------
__global__ void k_count(const int* __restrict__ dst, int* __restrict__ deg) {
    int e = blockIdx.x * 256 + threadIdx.x;
    if (e < N_EDGES) atomicAdd(&deg[dst[e]], 1);
}

__global__ void k_scan1(const int* __restrict__ deg, int* __restrict__ chunkSums) {
    __shared__ int sh[256];
    int base = blockIdx.x * SCAN_CHUNK;
    int t = threadIdx.x;
    int s = 0;
#pragma unroll
    for (int i = 0; i < 4; i++) {
        int idx = base + t * 4 + i;
        if (idx < N_NODES) s += deg[idx];
    }
    sh[t] = s;
    __syncthreads();
    for (int off = 128; off > 0; off >>= 1) {
        if (t < off) sh[t] += sh[t + off];
        __syncthreads();
    }
    if (t == 0) chunkSums[blockIdx.x] = sh[0];
}

__global__ void k_scan2(int* chunkSums, int* offs) {
    if (threadIdx.x == 0) {
        int run = 0;
        for (int i = 0; i < NCHUNKS; i++) {
            int v = chunkSums[i];
            chunkSums[i] = run;
            run += v;
        }
        offs[N_NODES] = run;
    }
}

__global__ void k_scan3(const int* __restrict__ deg, const int* __restrict__ chunkSums,
                        int* __restrict__ offs) {
    __shared__ int sh[256];
    int base = blockIdx.x * SCAN_CHUNK;
    int t = threadIdx.x;
    int v[4];
    int s = 0;
#pragma unroll
    for (int i = 0; i < 4; i++) {
        int idx = base + t * 4 + i;
        v[i] = (idx < N_NODES) ? deg[idx] : 0;
        s += v[i];
    }
    sh[t] = s;
    __syncthreads();
    for (int off = 1; off < 256; off <<= 1) {
        int x = sh[t];
        if (t >= off) x += sh[t - off];
        __syncthreads();
        sh[t] = x;
        __syncthreads();
    }
    int excl = sh[t] - s;
    int run = chunkSums[blockIdx.x] + excl;
#pragma unroll
    for (int i = 0; i < 4; i++) {
        int idx = base + t * 4 + i;
        if (idx < N_NODES) offs[idx] = run;
        run += v[i];
    }
}

__global__ void k_fill(const int* __restrict__ src, const int* __restrict__ dst,
                       const int* __restrict__ offs, int* __restrict__ cursor,
                       int* __restrict__ srcSorted) {
    int e = blockIdx.x * 256 + threadIdx.x;
    if (e < N_EDGES) {
        int d = dst[e];
        int pos = offs[d] + atomicAdd(&cursor[d], 1);
        srcSorted[pos] = src[e];
    }
}

// ---------------- x (f32) -> bf16 ----------------
__global__ void k_x2bf(const float* __restrict__ x, unsigned short* __restrict__ xbf) {
    int idx = blockIdx.x * 256 + threadIdx.x;    // chunks of 8
    if (idx >= N_NODES * HID / 8) return;
    const float4* p = (const float4*)&x[(size_t)idx * 8];
    float4 a = p[0], b = p[1];
    short8_t o = { (short)f2bf(a.x), (short)f2bf(a.y), (short)f2bf(a.z), (short)f2bf(a.w),
                   (short)f2bf(b.x), (short)f2bf(b.y), (short)f2bf(b.z), (short)f2bf(b.w) };
    *(short8_t*)&xbf[(size_t)idx * 8] = o;
}

// ---------------- Weight pre-pack into MFMA B-fragment order ----------------
// Wp[(ntile*4+ks)*64 + lane][j] = bf16( W[ks*32 + (lane>>4)*8 + j][ntile*16 + (lane&15)] )
__global__ void k_packW(const float* __restrict__ W1s, const float* __restrict__ W2s,
                        unsigned short* __restrict__ Wp) {
    int idx = blockIdx.x * 256 + threadIdx.x;   // 6 mats * 2048 frags
    if (idx >= 6 * 2048) return;
    int mat = idx >> 11;
    int rem = idx & 2047;
    int lane = rem & 63;
    int ks = (rem >> 6) & 3;
    int nt = rem >> 8;
    int l = mat >> 1;
    const float* W = (mat & 1) ? (W2s + (size_t)l * HID * HID) : (W1s + (size_t)l * HID * HID);
    int n = nt * 16 + (lane & 15);
    int k0 = ks * 32 + (lane >> 4) * 8;
    short8_t o;
#pragma unroll
    for (int j = 0; j < 8; j++) o[j] = (short)f2bf(W[(size_t)(k0 + j) * HID + n]);
    *(short8_t*)&Wp[(size_t)idx * 8] = o;
}

// ---------------- Aggregation (bf16): h0 = x + sum_{j->i} x_j ----------------
__global__ void k_agg(const unsigned short* __restrict__ xbf, const int* __restrict__ offs,
                      const int* __restrict__ srcSorted, unsigned short* __restrict__ h0bf) {
    int node = blockIdx.x * 8 + (threadIdx.x >> 5);
    int lane = threadIdx.x & 31;
    if (node >= N_NODES) return;
    int c = lane * 4;
    ushort4 own = *(const ushort4*)&xbf[(size_t)node * HID + c];
    float a0 = bf2f(own.x), a1 = bf2f(own.y), a2 = bf2f(own.z), a3 = bf2f(own.w);
    int e0 = offs[node], e1 = offs[node + 1];
    for (int e = e0; e < e1; e++) {
        int s = srcSorted[e];
        ushort4 v = *(const ushort4*)&xbf[(size_t)s * HID + c];
        a0 += bf2f(v.x); a1 += bf2f(v.y); a2 += bf2f(v.z); a3 += bf2f(v.w);
    }
    ushort4 o;
    o.x = f2bf(a0); o.y = f2bf(a1); o.z = f2bf(a2); o.w = f2bf(a3);
    *(ushort4*)&h0bf[(size_t)node * HID + c] = o;
}

// ---------------- Fused MFMA MLP + BN partial sums ----------------
// 64 rows/block, 4 waves, each wave: 16 rows x 128 cols = 8 tiles of 16x16, K-step 32.
#define PITCH 136   // bf16 elems per LDS row: 272 B = 16*17 -> 16B-aligned rows, stride breaks bank pattern

__global__ __launch_bounds__(256) void k_mlp(const unsigned short* __restrict__ h0bf,
                                             const unsigned short* __restrict__ W1p,
                                             const float* __restrict__ b1,
                                             const unsigned short* __restrict__ W2p,
                                             const float* __restrict__ b2,
                                             unsigned short* __restrict__ hbf,
                                             float* __restrict__ bnsum) {
    __shared__ __align__(16) unsigned short As[64 * PITCH];   // 17408 B
    __shared__ float bnS[2 * HID];

    int tid = threadIdx.x;
    int rowBase = blockIdx.x * 64;

    // stage A tile (bf16), zero-pad invalid rows
#pragma unroll
    for (int i = 0; i < 4; i++) {
        int fid = tid + i * 256;         // 0..1023 chunks of 8 bf16
        int r = fid >> 4;                // 16 chunks per 128-col row
        int c8 = (fid & 15) * 8;
        int gr = rowBase + r;
        short8_t v = { 0, 0, 0, 0, 0, 0, 0, 0 };
        if (gr < N_NODES) v = *(const short8_t*)&h0bf[(size_t)gr * HID + c8];
        *(short8_t*)&As[r * PITCH + c8] = v;
    }
    bnS[tid] = 0.f;                      // 256 threads cover 2*HID
    __syncthreads();

    int lane = tid & 63;
    int wave = tid >> 6;
    int lrow = lane & 15;
    int quad = lane >> 4;
    int mrow = wave * 16 + lrow;

    f32x4 acc[8];
#pragma unroll
    for (int t = 0; t < 8; t++) acc[t] = (f32x4){ 0.f, 0.f, 0.f, 0.f };

    // ---- GEMM1 ----
#pragma unroll
    for (int ks = 0; ks < 4; ks++) {
        short8_t a = *(const short8_t*)&As[mrow * PITCH + ks * 32 + quad * 8];
#pragma unroll
        for (int t = 0; t < 8; t++) {
            short8_t b = *(const short8_t*)&W1p[(size_t)((t * 4 + ks) * 64 + lane) * 8];
            acc[t] = __builtin_amdgcn_mfma_f32_16x16x32_bf16(a, b, acc[t], 0, 0, 0);
        }
    }
    __syncthreads();
    // bias + relu, T -> As (C-layout: row=quad*4+r, col=lrow within tile)
#pragma unroll
    for (int t = 0; t < 8; t++) {
        int col = t * 16 + lrow;
        float bb = b1[col];
#pragma unroll
        for (int r = 0; r < 4; r++) {
            float v = fmaxf(acc[t][r] + bb, 0.f);
            As[(wave * 16 + quad * 4 + r) * PITCH + col] = f2bf(v);
        }
    }
    __syncthreads();

#pragma unroll
    for (int t = 0; t < 8; t++) acc[t] = (f32x4){ 0.f, 0.f, 0.f, 0.f };

    // ---- GEMM2 ----
#pragma unroll
    for (int ks = 0; ks < 4; ks++) {
        short8_t a = *(const short8_t*)&As[mrow * PITCH + ks * 32 + quad * 8];
#pragma unroll
        for (int t = 0; t < 8; t++) {
            short8_t b = *(const short8_t*)&W2p[(size_t)((t * 4 + ks) * 64 + lane) * 8];
            acc[t] = __builtin_amdgcn_mfma_f32_16x16x32_bf16(a, b, acc[t], 0, 0, 0);
        }
    }
    __syncthreads();
    // bias + BN partials + C -> As (bf16) for vectorized store
#pragma unroll
    for (int t = 0; t < 8; t++) {
        int col = t * 16 + lrow;
        float bb = b2[col];
        float s1 = 0.f, s2 = 0.f;
#pragma unroll
        for (int r = 0; r < 4; r++) {
            int grow = rowBase + wave * 16 + quad * 4 + r;
            unsigned short bv = f2bf(acc[t][r] + bb);
            float vr = bf2f(bv);
            if (grow < N_NODES) { s1 += vr; s2 += vr * vr; }
            As[(wave * 16 + quad * 4 + r) * PITCH + col] = bv;
        }
        atomicAdd(&bnS[col], s1);
        atomicAdd(&bnS[HID + col], s2);
    }
    __syncthreads();
#pragma unroll
    for (int i = 0; i < 4; i++) {
        int fid = tid + i * 256;
        int r = fid >> 4;
        int c8 = (fid & 15) * 8;
        int gr = rowBase + r;
        if (gr < N_NODES)
            *(short8_t*)&hbf[(size_t)gr * HID + c8] = *(const short8_t*)&As[r * PITCH + c8];
    }
    atomicAdd(&bnsum[tid], bnS[tid]);
}

// ---------------- BN scale/shift ----------------
__global__ void k_bnscale(const float* __restrict__ bnsum, const float* __restrict__ gamma,
                          const float* __restrict__ beta, float* __restrict__ sc) {
    int c = threadIdx.x;
    if (c < HID) {
        float mean = bnsum[c] * (1.0f / N_NODES);
        float var = bnsum[HID + c] * (1.0f / N_NODES) - mean * mean;
        float s = gamma[c] * rsqrtf(var + BN_EPS);
        sc[c] = s;
        sc[HID + c] = beta[c] - mean * s;
    }
}

// ---------------- BN apply + ReLU (bf16 in/out) ----------------
__global__ void k_bnapply(const unsigned short* __restrict__ hbf, const float* __restrict__ sc,
                          unsigned short* __restrict__ xout) {
    int idx = blockIdx.x * 256 + threadIdx.x;   // chunks of 8
    if (idx >= N_NODES * HID / 8) return;
    int c8 = (idx & 15) * 8;
    short8_t v = *(const short8_t*)&hbf[(size_t)idx * 8];
    short8_t o;
#pragma unroll
    for (int j = 0; j < 8; j++) {
        float f = bf2f((unsigned short)v[j]);
        f = f * sc[c8 + j] + sc[HID + c8 + j];
        o[j] = (short)f2bf(fmaxf(f, 0.f));
    }
    *(short8_t*)&xout[(size_t)idx * 8] = o;
}

// ---------------- Pool (batch sorted -> segmented register accumulation) ----------------
#define POOL_CHUNK 512
__global__ void k_pool(const unsigned short* __restrict__ X, const int* __restrict__ batch,
                       float* __restrict__ g) {
    int lane = threadIdx.x & 31;
    int rg = threadIdx.x >> 5;
    int c = lane * 4;
    int base = blockIdx.x * POOL_CHUNK;
    int end = base + POOL_CHUNK;
    if (end > N_NODES) end = N_NODES;
    float a0 = 0.f, a1 = 0.f, a2 = 0.f, a3 = 0.f;
    int cur = -1;
    for (int r = base + rg; r < end; r += 8) {
        int b = batch[r];
        if (b != cur) {
            if (cur >= 0) {
                atomicAdd(&g[cur * HID + c + 0], a0);
                atomicAdd(&g[cur * HID + c + 1], a1);
                atomicAdd(&g[cur * HID + c + 2], a2);
                atomicAdd(&g[cur * HID + c + 3], a3);
            }
            cur = b;
            a0 = a1 = a2 = a3 = 0.f;
        }
        ushort4 v = *(const ushort4*)&X[(size_t)r * HID + c];
        a0 += bf2f(v.x); a1 += bf2f(v.y); a2 += bf2f(v.z); a3 += bf2f(v.w);
    }
    if (cur >= 0) {
        atomicAdd(&g[cur * HID + c + 0], a0);
        atomicAdd(&g[cur * HID + c + 1], a1);
        atomicAdd(&g[cur * HID + c + 2], a2);
        atomicAdd(&g[cur * HID + c + 3], a3);
    }
}

// ---------------- Final linear ----------------
__global__ void k_final(const float* __restrict__ g, const float* __restrict__ Wlin,
                        const float* __restrict__ blin, float* __restrict__ out) {
    int o = blockIdx.x * 256 + threadIdx.x;
    if (o >= N_GRAPHS * OUTC) return;
    int gi = o / OUTC, c = o % OUTC;
    float s = blin[c];
    for (int k = 0; k < HID; k++) s += g[gi * HID + k] * Wlin[k * OUTC + c];
    out[o] = s;
}

// ---------------- Launch ----------------
extern "C" void kernel_launch(void* const* d_in, const int* in_sizes, int n_in,
                              void* d_out, int out_size, void* d_ws, size_t ws_size,
                              hipStream_t stream) {
    const float* x      = (const float*)d_in[0];
    const float* W1s    = (const float*)d_in[1];
    const float* b1s    = (const float*)d_in[2];
    const float* W2s    = (const float*)d_in[3];
    const float* b2s    = (const float*)d_in[4];
    const float* gammas = (const float*)d_in[5];
    const float* betas  = (const float*)d_in[6];
    const float* Wlin   = (const float*)d_in[7];
    const float* blin   = (const float*)d_in[8];
    const int* edge_index = (const int*)d_in[9];
    const int* batch    = (const int*)d_in[10];
    float* out = (float*)d_out;

    const int* src = edge_index;
    const int* dst = edge_index + N_EDGES;

    // workspace layout (16B aligned offsets)
    char* w = (char*)d_ws;
    int* deg       = (int*)w;  w += (size_t)N_NODES * 4;            // 200000
    int* cursor    = (int*)w;  w += (size_t)N_NODES * 4;            // 200000
    int* offs      = (int*)w;  w += 200016;                         // 50001 ints, padded
    int* chunkSums = (int*)w;  w += 256;
    int* srcSorted = (int*)w;  w += (size_t)N_EDGES * 4;            // 3.2 MB
    unsigned short* Xbf  = (unsigned short*)w; w += (size_t)N_NODES * HID * 2;   // 12.8 MB
    unsigned short* H0bf = (unsigned short*)w; w += (size_t)N_NODES * HID * 2;
    unsigned short* Hbf  = (unsigned short*)w; w += (size_t)N_NODES * HID * 2;
    unsigned short* Wp   = (unsigned short*)w; w += (size_t)6 * 2048 * 8 * 2;    // 196608 B
    float* bnsum = (float*)w;  w += 2 * HID * 4;
    float* bnsc  = (float*)w;  w += 2 * HID * 4;
    float* g     = (float*)w;  w += (size_t)N_GRAPHS * HID * 4;

    hipMemsetAsync(deg, 0, (size_t)N_NODES * 4, stream);
    hipMemsetAsync(cursor, 0, (size_t)N_NODES * 4, stream);
    hipMemsetAsync(g, 0, (size_t)N_GRAPHS * HID * 4, stream);

    // CSR build + dtype prep
    k_count<<<(N_EDGES + 255) / 256, 256, 0, stream>>>(dst, deg);
    k_scan1<<<NCHUNKS, 256, 0, stream>>>(deg, chunkSums);
    k_scan2<<<1, 64, 0, stream>>>(chunkSums, offs);
    k_scan3<<<NCHUNKS, 256, 0, stream>>>(deg, chunkSums, offs);
    k_fill<<<(N_EDGES + 255) / 256, 256, 0, stream>>>(src, dst, offs, cursor, srcSorted);
    k_packW<<<(6 * 2048 + 255) / 256, 256, 0, stream>>>(W1s, W2s, Wp);
    k_x2bf<<<(N_NODES * HID / 8 + 255) / 256, 256, 0, stream>>>(x, Xbf);

    const unsigned short* xin = Xbf;
    for (int l = 0; l < 3; l++) {
        k_agg<<<(N_NODES + 7) / 8, 256, 0, stream>>>(xin, offs, srcSorted, H0bf);
        hipMemsetAsync(bnsum, 0, 2 * HID * 4, stream);
        k_mlp<<<(N_NODES + 63) / 64, 256, 0, stream>>>(
            H0bf, Wp + (size_t)(l * 2 + 0) * 16384, b1s + (size_t)l * HID,
            Wp + (size_t)(l * 2 + 1) * 16384, b2s + (size_t)l * HID, Hbf, bnsum);
        k_bnscale<<<1, 128, 0, stream>>>(bnsum, gammas + (size_t)l * HID,
                                         betas + (size_t)l * HID, bnsc);
        k_bnapply<<<(N_NODES * HID / 8 + 255) / 256, 256, 0, stream>>>(Hbf, bnsc, Xbf);
        xin = Xbf;
    }

    k_pool<<<(N_NODES + POOL_CHUNK - 1) / POOL_CHUNK, 256, 0, stream>>>(Xbf, batch, g);
    k_final<<<(N_GRAPHS * OUTC + 255) / 256, 256, 0, stream>>>(g, Wlin, blin, out);
}

// Round 3
// 501.102 us; speedup vs baseline: 1.5006x; 1.1234x over previous
//
#include <hip/hip_runtime.h>

#define N_NODES 50000
#define N_EDGES 800000
#define HID 128
#define OUTC 10
#define N_GRAPHS 64
#define BN_EPS 1e-5f

#define SCAN_CHUNK 1024
#define NCHUNKS ((N_NODES + SCAN_CHUNK - 1) / SCAN_CHUNK)   // 49

typedef __attribute__((ext_vector_type(8))) short short8_t;
typedef __attribute__((ext_vector_type(4))) float f32x4;

__device__ __forceinline__ unsigned short f2bf(float f) {
    unsigned u = __float_as_uint(f);
    u += 0x7FFFu + ((u >> 16) & 1u);     // RNE
    return (unsigned short)(u >> 16);
}
__device__ __forceinline__ float bf2f(unsigned short s) {
    return __uint_as_float(((unsigned)s) << 16);
}
// dword holding 2 bf16 -> 2 floats (2 VALU ops)
__device__ __forceinline__ float2 bfp2f(unsigned v) {
    float2 r;
    r.x = __uint_as_float(v << 16);
    r.y = __uint_as_float(v & 0xFFFF0000u);
    return r;
}

// ---------------- CSR build ----------------
__global__ void k_count(const int* __restrict__ dst, int* __restrict__ deg) {
    int e = blockIdx.x * 256 + threadIdx.x;
    if (e < N_EDGES) atomicAdd(&deg[dst[e]], 1);
}

__global__ void k_scan1(const int* __restrict__ deg, int* __restrict__ chunkSums) {
    __shared__ int sh[256];
    int base = blockIdx.x * SCAN_CHUNK;
    int t = threadIdx.x;
    int s = 0;
#pragma unroll
    for (int i = 0; i < 4; i++) {
        int idx = base + t * 4 + i;
        if (idx < N_NODES) s += deg[idx];
    }
    sh[t] = s;
    __syncthreads();
    for (int off = 128; off > 0; off >>= 1) {
        if (t < off) sh[t] += sh[t + off];
        __syncthreads();
    }
    if (t == 0) chunkSums[blockIdx.x] = sh[0];
}

__global__ void k_scan2(int* chunkSums, int* offs) {
    if (threadIdx.x == 0) {
        int run = 0;
        for (int i = 0; i < NCHUNKS; i++) {
            int v = chunkSums[i];
            chunkSums[i] = run;
            run += v;
        }
        offs[N_NODES] = run;
    }
}

__global__ void k_scan3(const int* __restrict__ deg, const int* __restrict__ chunkSums,
                        int* __restrict__ offs) {
    __shared__ int sh[256];
    int base = blockIdx.x * SCAN_CHUNK;
    int t = threadIdx.x;
    int v[4];
    int s = 0;
#pragma unroll
    for (int i = 0; i < 4; i++) {
        int idx = base + t * 4 + i;
        v[i] = (idx < N_NODES) ? deg[idx] : 0;
        s += v[i];
    }
    sh[t] = s;
    __syncthreads();
    for (int off = 1; off < 256; off <<= 1) {
        int x = sh[t];
        if (t >= off) x += sh[t - off];
        __syncthreads();
        sh[t] = x;
        __syncthreads();
    }
    int excl = sh[t] - s;
    int run = chunkSums[blockIdx.x] + excl;
#pragma unroll
    for (int i = 0; i < 4; i++) {
        int idx = base + t * 4 + i;
        if (idx < N_NODES) offs[idx] = run;
        run += v[i];
    }
}

__global__ void k_fill(const int* __restrict__ src, const int* __restrict__ dst,
                       const int* __restrict__ offs, int* __restrict__ cursor,
                       int* __restrict__ srcSorted) {
    int e = blockIdx.x * 256 + threadIdx.x;
    if (e < N_EDGES) {
        int d = dst[e];
        int pos = offs[d] + atomicAdd(&cursor[d], 1);
        srcSorted[pos] = src[e];
    }
}

// ---------------- x (f32) -> bf16 ----------------
__global__ void k_x2bf(const float* __restrict__ x, unsigned short* __restrict__ xbf) {
    int idx = blockIdx.x * 256 + threadIdx.x;    // chunks of 8
    if (idx >= N_NODES * HID / 8) return;
    const float4* p = (const float4*)&x[(size_t)idx * 8];
    float4 a = p[0], b = p[1];
    short8_t o = { (short)f2bf(a.x), (short)f2bf(a.y), (short)f2bf(a.z), (short)f2bf(a.w),
                   (short)f2bf(b.x), (short)f2bf(b.y), (short)f2bf(b.z), (short)f2bf(b.w) };
    *(short8_t*)&xbf[(size_t)idx * 8] = o;
}

// ---------------- Weight pre-pack into MFMA B-fragment order ----------------
__global__ void k_packW(const float* __restrict__ W1s, const float* __restrict__ W2s,
                        unsigned short* __restrict__ Wp) {
    int idx = blockIdx.x * 256 + threadIdx.x;   // 6 mats * 2048 frags
    if (idx >= 6 * 2048) return;
    int mat = idx >> 11;
    int rem = idx & 2047;
    int lane = rem & 63;
    int ks = (rem >> 6) & 3;
    int nt = rem >> 8;
    int l = mat >> 1;
    const float* W = (mat & 1) ? (W2s + (size_t)l * HID * HID) : (W1s + (size_t)l * HID * HID);
    int n = nt * 16 + (lane & 15);
    int k0 = ks * 32 + (lane >> 4) * 8;
    short8_t o;
#pragma unroll
    for (int j = 0; j < 8; j++) o[j] = (short)f2bf(W[(size_t)(k0 + j) * HID + n]);
    *(short8_t*)&Wp[(size_t)idx * 8] = o;
}

// ---------------- Aggregation, wave/node, optional fused BN+ReLU on input ----------------
// h0_i = t(x_i) + sum_{j->i} t(x_j),  t = BN? relu(v*s+b) : v
template <bool BN>
__global__ __launch_bounds__(256) void k_agg(const unsigned short* __restrict__ X,
                                             const float* __restrict__ sc,
                                             const int* __restrict__ offs,
                                             const int* __restrict__ srcSorted,
                                             unsigned short* __restrict__ h0) {
    int node = blockIdx.x * 4 + (threadIdx.x >> 6);   // 50000 = 4*12500, always full
    int lane = threadIdx.x & 63;
    int c = lane * 2;

    float s0 = 0.f, s1 = 0.f, b0 = 0.f, b1 = 0.f;
    if (BN) { s0 = sc[c]; s1 = sc[c + 1]; b0 = sc[HID + c]; b1 = sc[HID + c + 1]; }

    float2 own = bfp2f(*(const unsigned*)&X[(size_t)node * HID + c]);
    float a0, a1;
    if (BN) { a0 = fmaxf(own.x * s0 + b0, 0.f); a1 = fmaxf(own.y * s1 + b1, 0.f); }
    else    { a0 = own.x; a1 = own.y; }

    int e0 = offs[node];
    int deg = offs[node + 1] - e0;

    for (int base = 0; base < deg; base += 64) {
        int cnt = deg - base; if (cnt > 64) cnt = 64;
        int ii = base + lane;
        int myidx = srcSorted[e0 + (ii < deg ? ii : deg - 1)];
        int j = 0;
        for (; j + 8 <= cnt; j += 8) {
            int i0 = __shfl(myidx, j + 0), i1 = __shfl(myidx, j + 1);
            int i2 = __shfl(myidx, j + 2), i3 = __shfl(myidx, j + 3);
            int i4 = __shfl(myidx, j + 4), i5 = __shfl(myidx, j + 5);
            int i6 = __shfl(myidx, j + 6), i7 = __shfl(myidx, j + 7);
            unsigned v0 = *(const unsigned*)&X[(size_t)i0 * HID + c];
            unsigned v1 = *(const unsigned*)&X[(size_t)i1 * HID + c];
            unsigned v2 = *(const unsigned*)&X[(size_t)i2 * HID + c];
            unsigned v3 = *(const unsigned*)&X[(size_t)i3 * HID + c];
            unsigned v4 = *(const unsigned*)&X[(size_t)i4 * HID + c];
            unsigned v5 = *(const unsigned*)&X[(size_t)i5 * HID + c];
            unsigned v6 = *(const unsigned*)&X[(size_t)i6 * HID + c];
            unsigned v7 = *(const unsigned*)&X[(size_t)i7 * HID + c];
            float2 f0 = bfp2f(v0), f1 = bfp2f(v1), f2 = bfp2f(v2), f3 = bfp2f(v3);
            float2 f4 = bfp2f(v4), f5 = bfp2f(v5), f6 = bfp2f(v6), f7 = bfp2f(v7);
            if (BN) {
                a0 += fmaxf(f0.x * s0 + b0, 0.f); a1 += fmaxf(f0.y * s1 + b1, 0.f);
                a0 += fmaxf(f1.x * s0 + b0, 0.f); a1 += fmaxf(f1.y * s1 + b1, 0.f);
                a0 += fmaxf(f2.x * s0 + b0, 0.f); a1 += fmaxf(f2.y * s1 + b1, 0.f);
                a0 += fmaxf(f3.x * s0 + b0, 0.f); a1 += fmaxf(f3.y * s1 + b1, 0.f);
                a0 += fmaxf(f4.x * s0 + b0, 0.f); a1 += fmaxf(f4.y * s1 + b1, 0.f);
                a0 += fmaxf(f5.x * s0 + b0, 0.f); a1 += fmaxf(f5.y * s1 + b1, 0.f);
                a0 += fmaxf(f6.x * s0 + b0, 0.f); a1 += fmaxf(f6.y * s1 + b1, 0.f);
                a0 += fmaxf(f7.x * s0 + b0, 0.f); a1 += fmaxf(f7.y * s1 + b1, 0.f);
            } else {
                a0 += f0.x + f1.x + f2.x + f3.x + f4.x + f5.x + f6.x + f7.x;
                a1 += f0.y + f1.y + f2.y + f3.y + f4.y + f5.y + f6.y + f7.y;
            }
        }
        for (; j + 4 <= cnt; j += 4) {
            int i0 = __shfl(myidx, j + 0), i1 = __shfl(myidx, j + 1);
            int i2 = __shfl(myidx, j + 2), i3 = __shfl(myidx, j + 3);
            unsigned v0 = *(const unsigned*)&X[(size_t)i0 * HID + c];
            unsigned v1 = *(const unsigned*)&X[(size_t)i1 * HID + c];
            unsigned v2 = *(const unsigned*)&X[(size_t)i2 * HID + c];
            unsigned v3 = *(const unsigned*)&X[(size_t)i3 * HID + c];
            float2 f0 = bfp2f(v0), f1 = bfp2f(v1), f2 = bfp2f(v2), f3 = bfp2f(v3);
            if (BN) {
                a0 += fmaxf(f0.x * s0 + b0, 0.f); a1 += fmaxf(f0.y * s1 + b1, 0.f);
                a0 += fmaxf(f1.x * s0 + b0, 0.f); a1 += fmaxf(f1.y * s1 + b1, 0.f);
                a0 += fmaxf(f2.x * s0 + b0, 0.f); a1 += fmaxf(f2.y * s1 + b1, 0.f);
                a0 += fmaxf(f3.x * s0 + b0, 0.f); a1 += fmaxf(f3.y * s1 + b1, 0.f);
            } else {
                a0 += f0.x + f1.x + f2.x + f3.x;
                a1 += f0.y + f1.y + f2.y + f3.y;
            }
        }
        for (; j < cnt; j++) {
            int i0 = __shfl(myidx, j);
            float2 f0 = bfp2f(*(const unsigned*)&X[(size_t)i0 * HID + c]);
            if (BN) {
                a0 += fmaxf(f0.x * s0 + b0, 0.f); a1 += fmaxf(f0.y * s1 + b1, 0.f);
            } else {
                a0 += f0.x; a1 += f0.y;
            }
        }
    }

    unsigned o = (unsigned)f2bf(a0) | ((unsigned)f2bf(a1) << 16);
    *(unsigned*)&h0[(size_t)node * HID + c] = o;
}

// ---------------- Fused MFMA MLP + BN partial sums ----------------
#define PITCH 136

__global__ __launch_bounds__(256) void k_mlp(const unsigned short* __restrict__ h0bf,
                                             const unsigned short* __restrict__ W1p,
                                             const float* __restrict__ b1,
                                             const unsigned short* __restrict__ W2p,
                                             const float* __restrict__ b2,
                                             unsigned short* __restrict__ hbf,
                                             float* __restrict__ bnsum) {
    __shared__ __align__(16) unsigned short As[64 * PITCH];
    __shared__ float bnS[2 * HID];

    int tid = threadIdx.x;
    int rowBase = blockIdx.x * 64;

#pragma unroll
    for (int i = 0; i < 4; i++) {
        int fid = tid + i * 256;
        int r = fid >> 4;
        int c8 = (fid & 15) * 8;
        int gr = rowBase + r;
        short8_t v = { 0, 0, 0, 0, 0, 0, 0, 0 };
        if (gr < N_NODES) v = *(const short8_t*)&h0bf[(size_t)gr * HID + c8];
        *(short8_t*)&As[r * PITCH + c8] = v;
    }
    bnS[tid] = 0.f;
    __syncthreads();

    int lane = tid & 63;
    int wave = tid >> 6;
    int lrow = lane & 15;
    int quad = lane >> 4;
    int mrow = wave * 16 + lrow;

    f32x4 acc[8];
#pragma unroll
    for (int t = 0; t < 8; t++) acc[t] = (f32x4){ 0.f, 0.f, 0.f, 0.f };

#pragma unroll
    for (int ks = 0; ks < 4; ks++) {
        short8_t a = *(const short8_t*)&As[mrow * PITCH + ks * 32 + quad * 8];
#pragma unroll
        for (int t = 0; t < 8; t++) {
            short8_t b = *(const short8_t*)&W1p[(size_t)((t * 4 + ks) * 64 + lane) * 8];
            acc[t] = __builtin_amdgcn_mfma_f32_16x16x32_bf16(a, b, acc[t], 0, 0, 0);
        }
    }
    __syncthreads();
#pragma unroll
    for (int t = 0; t < 8; t++) {
        int col = t * 16 + lrow;
        float bb = b1[col];
#pragma unroll
        for (int r = 0; r < 4; r++) {
            float v = fmaxf(acc[t][r] + bb, 0.f);
            As[(wave * 16 + quad * 4 + r) * PITCH + col] = f2bf(v);
        }
    }
    __syncthreads();

#pragma unroll
    for (int t = 0; t < 8; t++) acc[t] = (f32x4){ 0.f, 0.f, 0.f, 0.f };

#pragma unroll
    for (int ks = 0; ks < 4; ks++) {
        short8_t a = *(const short8_t*)&As[mrow * PITCH + ks * 32 + quad * 8];
#pragma unroll
        for (int t = 0; t < 8; t++) {
            short8_t b = *(const short8_t*)&W2p[(size_t)((t * 4 + ks) * 64 + lane) * 8];
            acc[t] = __builtin_amdgcn_mfma_f32_16x16x32_bf16(a, b, acc[t], 0, 0, 0);
        }
    }
    __syncthreads();
#pragma unroll
    for (int t = 0; t < 8; t++) {
        int col = t * 16 + lrow;
        float bb = b2[col];
        float s1 = 0.f, s2 = 0.f;
#pragma unroll
        for (int r = 0; r < 4; r++) {
            int grow = rowBase + wave * 16 + quad * 4 + r;
            unsigned short bv = f2bf(acc[t][r] + bb);
            float vr = bf2f(bv);
            if (grow < N_NODES) { s1 += vr; s2 += vr * vr; }
            As[(wave * 16 + quad * 4 + r) * PITCH + col] = bv;
        }
        atomicAdd(&bnS[col], s1);
        atomicAdd(&bnS[HID + col], s2);
    }
    __syncthreads();
#pragma unroll
    for (int i = 0; i < 4; i++) {
        int fid = tid + i * 256;
        int r = fid >> 4;
        int c8 = (fid & 15) * 8;
        int gr = rowBase + r;
        if (gr < N_NODES)
            *(short8_t*)&hbf[(size_t)gr * HID + c8] = *(const short8_t*)&As[r * PITCH + c8];
    }
    atomicAdd(&bnsum[tid], bnS[tid]);
}

// ---------------- BN scale/shift ----------------
__global__ void k_bnscale(const float* __restrict__ bnsum, const float* __restrict__ gamma,
                          const float* __restrict__ beta, float* __restrict__ sc) {
    int c = threadIdx.x;
    if (c < HID) {
        float mean = bnsum[c] * (1.0f / N_NODES);
        float var = bnsum[HID + c] * (1.0f / N_NODES) - mean * mean;
        float s = gamma[c] * rsqrtf(var + BN_EPS);
        sc[c] = s;
        sc[HID + c] = beta[c] - mean * s;
    }
}

// ---------------- Pool with fused BN+ReLU (batch sorted) ----------------
#define POOL_CHUNK 512
__global__ void k_pool(const unsigned short* __restrict__ X, const float* __restrict__ sc,
                       const int* __restrict__ batch, float* __restrict__ g) {
    int lane = threadIdx.x & 31;
    int rg = threadIdx.x >> 5;
    int c = lane * 4;
    float4 s = *(const float4*)&sc[c];
    float4 b = *(const float4*)&sc[HID + c];
    int base = blockIdx.x * POOL_CHUNK;
    int end = base + POOL_CHUNK;
    if (end > N_NODES) end = N_NODES;
    float a0 = 0.f, a1 = 0.f, a2 = 0.f, a3 = 0.f;
    int cur = -1;
    for (int r = base + rg; r < end; r += 8) {
        int bb = batch[r];
        if (bb != cur) {
            if (cur >= 0) {
                atomicAdd(&g[cur * HID + c + 0], a0);
                atomicAdd(&g[cur * HID + c + 1], a1);
                atomicAdd(&g[cur * HID + c + 2], a2);
                atomicAdd(&g[cur * HID + c + 3], a3);
            }
            cur = bb;
            a0 = a1 = a2 = a3 = 0.f;
        }
        ushort4 v = *(const ushort4*)&X[(size_t)r * HID + c];
        a0 += fmaxf(bf2f(v.x) * s.x + b.x, 0.f);
        a1 += fmaxf(bf2f(v.y) * s.y + b.y, 0.f);
        a2 += fmaxf(bf2f(v.z) * s.z + b.z, 0.f);
        a3 += fmaxf(bf2f(v.w) * s.w + b.w, 0.f);
    }
    if (cur >= 0) {
        atomicAdd(&g[cur * HID + c + 0], a0);
        atomicAdd(&g[cur * HID + c + 1], a1);
        atomicAdd(&g[cur * HID + c + 2], a2);
        atomicAdd(&g[cur * HID + c + 3], a3);
    }
}

// ---------------- Final linear ----------------
__global__ void k_final(const float* __restrict__ g, const float* __restrict__ Wlin,
                        const float* __restrict__ blin, float* __restrict__ out) {
    int o = blockIdx.x * 256 + threadIdx.x;
    if (o >= N_GRAPHS * OUTC) return;
    int gi = o / OUTC, c = o % OUTC;
    float s = blin[c];
    for (int k = 0; k < HID; k++) s += g[gi * HID + k] * Wlin[k * OUTC + c];
    out[o] = s;
}

// ---------------- Launch ----------------
extern "C" void kernel_launch(void* const* d_in, const int* in_sizes, int n_in,
                              void* d_out, int out_size, void* d_ws, size_t ws_size,
                              hipStream_t stream) {
    const float* x      = (const float*)d_in[0];
    const float* W1s    = (const float*)d_in[1];
    const float* b1s    = (const float*)d_in[2];
    const float* W2s    = (const float*)d_in[3];
    const float* b2s    = (const float*)d_in[4];
    const float* gammas = (const float*)d_in[5];
    const float* betas  = (const float*)d_in[6];
    const float* Wlin   = (const float*)d_in[7];
    const float* blin   = (const float*)d_in[8];
    const int* edge_index = (const int*)d_in[9];
    const int* batch    = (const int*)d_in[10];
    float* out = (float*)d_out;

    const int* src = edge_index;
    const int* dst = edge_index + N_EDGES;

    char* w = (char*)d_ws;
    int* deg       = (int*)w;  w += (size_t)N_NODES * 4;
    int* cursor    = (int*)w;  w += (size_t)N_NODES * 4;
    int* offs      = (int*)w;  w += 200016;
    int* chunkSums = (int*)w;  w += 256;
    int* srcSorted = (int*)w;  w += (size_t)N_EDGES * 4;
    unsigned short* Xbf  = (unsigned short*)w; w += (size_t)N_NODES * HID * 2;
    unsigned short* H0bf = (unsigned short*)w; w += (size_t)N_NODES * HID * 2;
    unsigned short* Hbf  = (unsigned short*)w; w += (size_t)N_NODES * HID * 2;
    unsigned short* Wp   = (unsigned short*)w; w += (size_t)6 * 2048 * 8 * 2;
    float* bnsum = (float*)w;  w += 2 * HID * 4;
    float* bnsc  = (float*)w;  w += 2 * HID * 4;
    float* g     = (float*)w;  w += (size_t)N_GRAPHS * HID * 4;

    hipMemsetAsync(deg, 0, (size_t)N_NODES * 4, stream);
    hipMemsetAsync(cursor, 0, (size_t)N_NODES * 4, stream);
    hipMemsetAsync(g, 0, (size_t)N_GRAPHS * HID * 4, stream);

    k_count<<<(N_EDGES + 255) / 256, 256, 0, stream>>>(dst, deg);
    k_scan1<<<NCHUNKS, 256, 0, stream>>>(deg, chunkSums);
    k_scan2<<<1, 64, 0, stream>>>(chunkSums, offs);
    k_scan3<<<NCHUNKS, 256, 0, stream>>>(deg, chunkSums, offs);
    k_fill<<<(N_EDGES + 255) / 256, 256, 0, stream>>>(src, dst, offs, cursor, srcSorted);
    k_packW<<<(6 * 2048 + 255) / 256, 256, 0, stream>>>(W1s, W2s, Wp);
    k_x2bf<<<(N_NODES * HID / 8 + 255) / 256, 256, 0, stream>>>(x, Xbf);

    const int aggBlocks = N_NODES / 4;   // 12500, exact
    for (int l = 0; l < 3; l++) {
        if (l == 0)
            k_agg<false><<<aggBlocks, 256, 0, stream>>>(Xbf, nullptr, offs, srcSorted, H0bf);
        else
            k_agg<true><<<aggBlocks, 256, 0, stream>>>(Hbf, bnsc, offs, srcSorted, H0bf);
        hipMemsetAsync(bnsum, 0, 2 * HID * 4, stream);
        k_mlp<<<(N_NODES + 63) / 64, 256, 0, stream>>>(
            H0bf, Wp + (size_t)(l * 2 + 0) * 16384, b1s + (size_t)l * HID,
            Wp + (size_t)(l * 2 + 1) * 16384, b2s + (size_t)l * HID, Hbf, bnsum);
        k_bnscale<<<1, 128, 0, stream>>>(bnsum, gammas + (size_t)l * HID,
                                         betas + (size_t)l * HID, bnsc);
    }

    k_pool<<<(N_NODES + POOL_CHUNK - 1) / POOL_CHUNK, 256, 0, stream>>>(Hbf, bnsc, batch, g);
    k_final<<<(N_GRAPHS * OUTC + 255) / 256, 256, 0, stream>>>(g, Wlin, blin, out);
}

// Round 4
// 447.636 us; speedup vs baseline: 1.6799x; 1.1194x over previous
//
#include <hip/hip_runtime.h>

#define N_NODES 50000
#define N_EDGES 800000
#define HID 128
#define OUTC 10
#define N_GRAPHS 64
#define BN_EPS 1e-5f

#define SCAN_CHUNK 1024
#define NCHUNKS ((N_NODES + SCAN_CHUNK - 1) / SCAN_CHUNK)   // 49
#define MLP_BLOCKS (N_NODES / 16)                           // 3125, exact

typedef __attribute__((ext_vector_type(8))) short short8_t;
typedef __attribute__((ext_vector_type(4))) float f32x4;

__device__ __forceinline__ unsigned short f2bf(float f) {
    unsigned u = __float_as_uint(f);
    u += 0x7FFFu + ((u >> 16) & 1u);     // RNE
    return (unsigned short)(u >> 16);
}
__device__ __forceinline__ float bf2f(unsigned short s) {
    return __uint_as_float(((unsigned)s) << 16);
}
__device__ __forceinline__ float2 bfp2f(unsigned v) {
    float2 r;
    r.x = __uint_as_float(v << 16);
    r.y = __uint_as_float(v & 0xFFFF0000u);
    return r;
}

// ---------------- CSR build ----------------
__global__ void k_count(const int* __restrict__ dst, int* __restrict__ deg) {
    int e = blockIdx.x * 256 + threadIdx.x;
    if (e < N_EDGES) atomicAdd(&deg[dst[e]], 1);
}

__global__ void k_scan1(const int* __restrict__ deg, int* __restrict__ chunkSums) {
    __shared__ int sh[256];
    int base = blockIdx.x * SCAN_CHUNK;
    int t = threadIdx.x;
    int s = 0;
#pragma unroll
    for (int i = 0; i < 4; i++) {
        int idx = base + t * 4 + i;
        if (idx < N_NODES) s += deg[idx];
    }
    sh[t] = s;
    __syncthreads();
    for (int off = 128; off > 0; off >>= 1) {
        if (t < off) sh[t] += sh[t + off];
        __syncthreads();
    }
    if (t == 0) chunkSums[blockIdx.x] = sh[0];
}

__global__ void k_scan2(int* chunkSums, int* offs) {
    if (threadIdx.x == 0) {
        int run = 0;
        for (int i = 0; i < NCHUNKS; i++) {
            int v = chunkSums[i];
            chunkSums[i] = run;
            run += v;
        }
        offs[N_NODES] = run;
    }
}

__global__ void k_scan3(const int* __restrict__ deg, const int* __restrict__ chunkSums,
                        int* __restrict__ offs) {
    __shared__ int sh[256];
    int base = blockIdx.x * SCAN_CHUNK;
    int t = threadIdx.x;
    int v[4];
    int s = 0;
#pragma unroll
    for (int i = 0; i < 4; i++) {
        int idx = base + t * 4 + i;
        v[i] = (idx < N_NODES) ? deg[idx] : 0;
        s += v[i];
    }
    sh[t] = s;
    __syncthreads();
    for (int off = 1; off < 256; off <<= 1) {
        int x = sh[t];
        if (t >= off) x += sh[t - off];
        __syncthreads();
        sh[t] = x;
        __syncthreads();
    }
    int excl = sh[t] - s;
    int run = chunkSums[blockIdx.x] + excl;
#pragma unroll
    for (int i = 0; i < 4; i++) {
        int idx = base + t * 4 + i;
        if (idx < N_NODES) offs[idx] = run;
        run += v[i];
    }
}

__global__ void k_fill(const int* __restrict__ src, const int* __restrict__ dst,
                       const int* __restrict__ offs, int* __restrict__ cursor,
                       int* __restrict__ srcSorted) {
    int e = blockIdx.x * 256 + threadIdx.x;
    if (e < N_EDGES) {
        int d = dst[e];
        int pos = offs[d] + atomicAdd(&cursor[d], 1);
        srcSorted[pos] = src[e];
    }
}

// ---------------- x (f32) -> bf16 ----------------
__global__ void k_x2bf(const float* __restrict__ x, unsigned short* __restrict__ xbf) {
    int idx = blockIdx.x * 256 + threadIdx.x;
    if (idx >= N_NODES * HID / 8) return;
    const float4* p = (const float4*)&x[(size_t)idx * 8];
    float4 a = p[0], b = p[1];
    short8_t o = { (short)f2bf(a.x), (short)f2bf(a.y), (short)f2bf(a.z), (short)f2bf(a.w),
                   (short)f2bf(b.x), (short)f2bf(b.y), (short)f2bf(b.z), (short)f2bf(b.w) };
    *(short8_t*)&xbf[(size_t)idx * 8] = o;
}

// ---------------- Weight pre-pack into MFMA B-fragment order ----------------
__global__ void k_packW(const float* __restrict__ W1s, const float* __restrict__ W2s,
                        unsigned short* __restrict__ Wp) {
    int idx = blockIdx.x * 256 + threadIdx.x;
    if (idx >= 6 * 2048) return;
    int mat = idx >> 11;
    int rem = idx & 2047;
    int lane = rem & 63;
    int ks = (rem >> 6) & 3;
    int nt = rem >> 8;
    int l = mat >> 1;
    const float* W = (mat & 1) ? (W2s + (size_t)l * HID * HID) : (W1s + (size_t)l * HID * HID);
    int n = nt * 16 + (lane & 15);
    int k0 = ks * 32 + (lane >> 4) * 8;
    short8_t o;
#pragma unroll
    for (int j = 0; j < 8; j++) o[j] = (short)f2bf(W[(size_t)(k0 + j) * HID + n]);
    *(short8_t*)&Wp[(size_t)idx * 8] = o;
}

// ---------------- Aggregation, wave/node, optional fused BN+ReLU on input ----------------
template <bool BN>
__global__ __launch_bounds__(256) void k_agg(const unsigned short* __restrict__ X,
                                             const float* __restrict__ sc,
                                             const int* __restrict__ offs,
                                             const int* __restrict__ srcSorted,
                                             unsigned short* __restrict__ h0) {
    int node = blockIdx.x * 4 + (threadIdx.x >> 6);
    int lane = threadIdx.x & 63;
    int c = lane * 2;

    float s0 = 0.f, s1 = 0.f, b0 = 0.f, b1 = 0.f;
    if (BN) { s0 = sc[c]; s1 = sc[c + 1]; b0 = sc[HID + c]; b1 = sc[HID + c + 1]; }

    float2 own = bfp2f(*(const unsigned*)&X[(size_t)node * HID + c]);
    float a0, a1;
    if (BN) { a0 = fmaxf(own.x * s0 + b0, 0.f); a1 = fmaxf(own.y * s1 + b1, 0.f); }
    else    { a0 = own.x; a1 = own.y; }

    int e0 = offs[node];
    int deg = offs[node + 1] - e0;

    for (int base = 0; base < deg; base += 64) {
        int cnt = deg - base; if (cnt > 64) cnt = 64;
        int ii = base + lane;
        int myidx = srcSorted[e0 + (ii < deg ? ii : deg - 1)];
        int j = 0;
        for (; j + 8 <= cnt; j += 8) {
            int i0 = __shfl(myidx, j + 0), i1 = __shfl(myidx, j + 1);
            int i2 = __shfl(myidx, j + 2), i3 = __shfl(myidx, j + 3);
            int i4 = __shfl(myidx, j + 4), i5 = __shfl(myidx, j + 5);
            int i6 = __shfl(myidx, j + 6), i7 = __shfl(myidx, j + 7);
            unsigned v0 = *(const unsigned*)&X[(size_t)i0 * HID + c];
            unsigned v1 = *(const unsigned*)&X[(size_t)i1 * HID + c];
            unsigned v2 = *(const unsigned*)&X[(size_t)i2 * HID + c];
            unsigned v3 = *(const unsigned*)&X[(size_t)i3 * HID + c];
            unsigned v4 = *(const unsigned*)&X[(size_t)i4 * HID + c];
            unsigned v5 = *(const unsigned*)&X[(size_t)i5 * HID + c];
            unsigned v6 = *(const unsigned*)&X[(size_t)i6 * HID + c];
            unsigned v7 = *(const unsigned*)&X[(size_t)i7 * HID + c];
            float2 f0 = bfp2f(v0), f1 = bfp2f(v1), f2 = bfp2f(v2), f3 = bfp2f(v3);
            float2 f4 = bfp2f(v4), f5 = bfp2f(v5), f6 = bfp2f(v6), f7 = bfp2f(v7);
            if (BN) {
                a0 += fmaxf(f0.x * s0 + b0, 0.f); a1 += fmaxf(f0.y * s1 + b1, 0.f);
                a0 += fmaxf(f1.x * s0 + b0, 0.f); a1 += fmaxf(f1.y * s1 + b1, 0.f);
                a0 += fmaxf(f2.x * s0 + b0, 0.f); a1 += fmaxf(f2.y * s1 + b1, 0.f);
                a0 += fmaxf(f3.x * s0 + b0, 0.f); a1 += fmaxf(f3.y * s1 + b1, 0.f);
                a0 += fmaxf(f4.x * s0 + b0, 0.f); a1 += fmaxf(f4.y * s1 + b1, 0.f);
                a0 += fmaxf(f5.x * s0 + b0, 0.f); a1 += fmaxf(f5.y * s1 + b1, 0.f);
                a0 += fmaxf(f6.x * s0 + b0, 0.f); a1 += fmaxf(f6.y * s1 + b1, 0.f);
                a0 += fmaxf(f7.x * s0 + b0, 0.f); a1 += fmaxf(f7.y * s1 + b1, 0.f);
            } else {
                a0 += f0.x + f1.x + f2.x + f3.x + f4.x + f5.x + f6.x + f7.x;
                a1 += f0.y + f1.y + f2.y + f3.y + f4.y + f5.y + f6.y + f7.y;
            }
        }
        for (; j + 4 <= cnt; j += 4) {
            int i0 = __shfl(myidx, j + 0), i1 = __shfl(myidx, j + 1);
            int i2 = __shfl(myidx, j + 2), i3 = __shfl(myidx, j + 3);
            unsigned v0 = *(const unsigned*)&X[(size_t)i0 * HID + c];
            unsigned v1 = *(const unsigned*)&X[(size_t)i1 * HID + c];
            unsigned v2 = *(const unsigned*)&X[(size_t)i2 * HID + c];
            unsigned v3 = *(const unsigned*)&X[(size_t)i3 * HID + c];
            float2 f0 = bfp2f(v0), f1 = bfp2f(v1), f2 = bfp2f(v2), f3 = bfp2f(v3);
            if (BN) {
                a0 += fmaxf(f0.x * s0 + b0, 0.f); a1 += fmaxf(f0.y * s1 + b1, 0.f);
                a0 += fmaxf(f1.x * s0 + b0, 0.f); a1 += fmaxf(f1.y * s1 + b1, 0.f);
                a0 += fmaxf(f2.x * s0 + b0, 0.f); a1 += fmaxf(f2.y * s1 + b1, 0.f);
                a0 += fmaxf(f3.x * s0 + b0, 0.f); a1 += fmaxf(f3.y * s1 + b1, 0.f);
            } else {
                a0 += f0.x + f1.x + f2.x + f3.x;
                a1 += f0.y + f1.y + f2.y + f3.y;
            }
        }
        for (; j < cnt; j++) {
            int i0 = __shfl(myidx, j);
            float2 f0 = bfp2f(*(const unsigned*)&X[(size_t)i0 * HID + c]);
            if (BN) {
                a0 += fmaxf(f0.x * s0 + b0, 0.f); a1 += fmaxf(f0.y * s1 + b1, 0.f);
            } else {
                a0 += f0.x; a1 += f0.y;
            }
        }
    }

    unsigned o = (unsigned)f2bf(a0) | ((unsigned)f2bf(a1) << 16);
    *(unsigned*)&h0[(size_t)node * HID + c] = o;
}

// ---------------- MFMA MLP, one wave per 16-row tile, atomic-free BN partials ----------------
#define MPITCH 136   // bf16 elems; 272 B rows, 16B-aligned

__global__ __launch_bounds__(64) void k_mlp(const unsigned short* __restrict__ h0bf,
                                            const unsigned short* __restrict__ W1p,
                                            const float* __restrict__ b1,
                                            const unsigned short* __restrict__ W2p,
                                            const float* __restrict__ b2,
                                            unsigned short* __restrict__ hbf,
                                            float* __restrict__ bnpart) {
    __shared__ __align__(16) unsigned short Ts[16 * MPITCH];   // 4352 B

    int lane = threadIdx.x;
    int lrow = lane & 15;
    int quad = lane >> 4;
    int rowBase = blockIdx.x * 16;   // exact: 3125*16 = 50000

    const unsigned short* Arow = h0bf + (size_t)(rowBase + lrow) * HID;

    f32x4 acc[8];
#pragma unroll
    for (int t = 0; t < 8; t++) acc[t] = (f32x4){ 0.f, 0.f, 0.f, 0.f };

    // A fragments straight from global: lane needs row (lane&15), k = ks*32 + quad*8 + j
    short8_t a0f = *(const short8_t*)&Arow[0 * 32 + quad * 8];
    short8_t a1f = *(const short8_t*)&Arow[1 * 32 + quad * 8];
    short8_t a2f = *(const short8_t*)&Arow[2 * 32 + quad * 8];
    short8_t a3f = *(const short8_t*)&Arow[3 * 32 + quad * 8];

    // ---- GEMM1 ----
#pragma unroll
    for (int t = 0; t < 8; t++) {
        short8_t b0 = *(const short8_t*)&W1p[(size_t)((t * 4 + 0) * 64 + lane) * 8];
        short8_t b1_ = *(const short8_t*)&W1p[(size_t)((t * 4 + 1) * 64 + lane) * 8];
        short8_t b2_ = *(const short8_t*)&W1p[(size_t)((t * 4 + 2) * 64 + lane) * 8];
        short8_t b3 = *(const short8_t*)&W1p[(size_t)((t * 4 + 3) * 64 + lane) * 8];
        acc[t] = __builtin_amdgcn_mfma_f32_16x16x32_bf16(a0f, b0, acc[t], 0, 0, 0);
        acc[t] = __builtin_amdgcn_mfma_f32_16x16x32_bf16(a1f, b1_, acc[t], 0, 0, 0);
        acc[t] = __builtin_amdgcn_mfma_f32_16x16x32_bf16(a2f, b2_, acc[t], 0, 0, 0);
        acc[t] = __builtin_amdgcn_mfma_f32_16x16x32_bf16(a3f, b3, acc[t], 0, 0, 0);
    }

    // bias + relu, C-layout -> Ts
#pragma unroll
    for (int t = 0; t < 8; t++) {
        int col = t * 16 + lrow;
        float bb = b1[col];
#pragma unroll
        for (int r = 0; r < 4; r++) {
            float v = fmaxf(acc[t][r] + bb, 0.f);
            Ts[(quad * 4 + r) * MPITCH + col] = f2bf(v);
        }
    }
    __syncthreads();

    // re-load A fragments for GEMM2 from Ts
    short8_t t0f = *(const short8_t*)&Ts[lrow * MPITCH + 0 * 32 + quad * 8];
    short8_t t1f = *(const short8_t*)&Ts[lrow * MPITCH + 1 * 32 + quad * 8];
    short8_t t2f = *(const short8_t*)&Ts[lrow * MPITCH + 2 * 32 + quad * 8];
    short8_t t3f = *(const short8_t*)&Ts[lrow * MPITCH + 3 * 32 + quad * 8];

#pragma unroll
    for (int t = 0; t < 8; t++) acc[t] = (f32x4){ 0.f, 0.f, 0.f, 0.f };

    // ---- GEMM2 ----
#pragma unroll
    for (int t = 0; t < 8; t++) {
        short8_t b0 = *(const short8_t*)&W2p[(size_t)((t * 4 + 0) * 64 + lane) * 8];
        short8_t b1_ = *(const short8_t*)&W2p[(size_t)((t * 4 + 1) * 64 + lane) * 8];
        short8_t b2_ = *(const short8_t*)&W2p[(size_t)((t * 4 + 2) * 64 + lane) * 8];
        short8_t b3 = *(const short8_t*)&W2p[(size_t)((t * 4 + 3) * 64 + lane) * 8];
        acc[t] = __builtin_amdgcn_mfma_f32_16x16x32_bf16(t0f, b0, acc[t], 0, 0, 0);
        acc[t] = __builtin_amdgcn_mfma_f32_16x16x32_bf16(t1f, b1_, acc[t], 0, 0, 0);
        acc[t] = __builtin_amdgcn_mfma_f32_16x16x32_bf16(t2f, b2_, acc[t], 0, 0, 0);
        acc[t] = __builtin_amdgcn_mfma_f32_16x16x32_bf16(t3f, b3, acc[t], 0, 0, 0);
    }
    __syncthreads();   // Ts reads done before overwrite

    // bias + pack + BN sums (quad-reduced, no atomics)
    float s1v[8], s2v[8];
#pragma unroll
    for (int t = 0; t < 8; t++) {
        int col = t * 16 + lrow;
        float bb = b2[col];
        float s1 = 0.f, s2 = 0.f;
#pragma unroll
        for (int r = 0; r < 4; r++) {
            unsigned short bv = f2bf(acc[t][r] + bb);
            float vr = bf2f(bv);
            s1 += vr; s2 += vr * vr;
            Ts[(quad * 4 + r) * MPITCH + col] = bv;
        }
        s1 += __shfl_xor(s1, 16); s1 += __shfl_xor(s1, 32);
        s2 += __shfl_xor(s2, 16); s2 += __shfl_xor(s2, 32);
        s1v[t] = s1; s2v[t] = s2;
    }
    __syncthreads();

    // vectorized store of the 16x128 tile
    unsigned short* Orow = hbf + (size_t)(rowBase + lrow) * HID;
#pragma unroll
    for (int cc = 0; cc < 4; cc++)
        *(short8_t*)&Orow[cc * 32 + quad * 8] = *(const short8_t*)&Ts[lrow * MPITCH + cc * 32 + quad * 8];

    if (quad == 0) {
        float* bp = bnpart + (size_t)blockIdx.x * 256;
#pragma unroll
        for (int t = 0; t < 8; t++) {
            bp[t * 16 + lrow] = s1v[t];
            bp[128 + t * 16 + lrow] = s2v[t];
        }
    }
}

// ---------------- BN partial reduce ----------------
__global__ void k_bnred(const float* __restrict__ bnpart, float* __restrict__ bnsum) {
    float acc = 0.f;
    for (int r = blockIdx.x; r < MLP_BLOCKS; r += 64)
        acc += bnpart[(size_t)r * 256 + threadIdx.x];
    atomicAdd(&bnsum[threadIdx.x], acc);
}

// ---------------- BN scale/shift ----------------
__global__ void k_bnscale(const float* __restrict__ bnsum, const float* __restrict__ gamma,
                          const float* __restrict__ beta, float* __restrict__ sc) {
    int c = threadIdx.x;
    if (c < HID) {
        float mean = bnsum[c] * (1.0f / N_NODES);
        float var = bnsum[HID + c] * (1.0f / N_NODES) - mean * mean;
        float s = gamma[c] * rsqrtf(var + BN_EPS);
        sc[c] = s;
        sc[HID + c] = beta[c] - mean * s;
    }
}

// ---------------- Pool with fused BN+ReLU (batch sorted) ----------------
#define POOL_CHUNK 512
__global__ void k_pool(const unsigned short* __restrict__ X, const float* __restrict__ sc,
                       const int* __restrict__ batch, float* __restrict__ g) {
    int lane = threadIdx.x & 31;
    int rg = threadIdx.x >> 5;
    int c = lane * 4;
    float4 s = *(const float4*)&sc[c];
    float4 b = *(const float4*)&sc[HID + c];
    int base = blockIdx.x * POOL_CHUNK;
    int end = base + POOL_CHUNK;
    if (end > N_NODES) end = N_NODES;
    float a0 = 0.f, a1 = 0.f, a2 = 0.f, a3 = 0.f;
    int cur = -1;
    for (int r = base + rg; r < end; r += 8) {
        int bb = batch[r];
        if (bb != cur) {
            if (cur >= 0) {
                atomicAdd(&g[cur * HID + c + 0], a0);
                atomicAdd(&g[cur * HID + c + 1], a1);
                atomicAdd(&g[cur * HID + c + 2], a2);
                atomicAdd(&g[cur * HID + c + 3], a3);
            }
            cur = bb;
            a0 = a1 = a2 = a3 = 0.f;
        }
        ushort4 v = *(const ushort4*)&X[(size_t)r * HID + c];
        a0 += fmaxf(bf2f(v.x) * s.x + b.x, 0.f);
        a1 += fmaxf(bf2f(v.y) * s.y + b.y, 0.f);
        a2 += fmaxf(bf2f(v.z) * s.z + b.z, 0.f);
        a3 += fmaxf(bf2f(v.w) * s.w + b.w, 0.f);
    }
    if (cur >= 0) {
        atomicAdd(&g[cur * HID + c + 0], a0);
        atomicAdd(&g[cur * HID + c + 1], a1);
        atomicAdd(&g[cur * HID + c + 2], a2);
        atomicAdd(&g[cur * HID + c + 3], a3);
    }
}

// ---------------- Final linear ----------------
__global__ void k_final(const float* __restrict__ g, const float* __restrict__ Wlin,
                        const float* __restrict__ blin, float* __restrict__ out) {
    int o = blockIdx.x * 256 + threadIdx.x;
    if (o >= N_GRAPHS * OUTC) return;
    int gi = o / OUTC, c = o % OUTC;
    float s = blin[c];
    for (int k = 0; k < HID; k++) s += g[gi * HID + k] * Wlin[k * OUTC + c];
    out[o] = s;
}

// ---------------- Launch ----------------
extern "C" void kernel_launch(void* const* d_in, const int* in_sizes, int n_in,
                              void* d_out, int out_size, void* d_ws, size_t ws_size,
                              hipStream_t stream) {
    const float* x      = (const float*)d_in[0];
    const float* W1s    = (const float*)d_in[1];
    const float* b1s    = (const float*)d_in[2];
    const float* W2s    = (const float*)d_in[3];
    const float* b2s    = (const float*)d_in[4];
    const float* gammas = (const float*)d_in[5];
    const float* betas  = (const float*)d_in[6];
    const float* Wlin   = (const float*)d_in[7];
    const float* blin   = (const float*)d_in[8];
    const int* edge_index = (const int*)d_in[9];
    const int* batch    = (const int*)d_in[10];
    float* out = (float*)d_out;

    const int* src = edge_index;
    const int* dst = edge_index + N_EDGES;

    char* w = (char*)d_ws;
    int* deg       = (int*)w;  w += (size_t)N_NODES * 4;
    int* cursor    = (int*)w;  w += (size_t)N_NODES * 4;
    int* offs      = (int*)w;  w += 200016;
    int* chunkSums = (int*)w;  w += 256;
    int* srcSorted = (int*)w;  w += (size_t)N_EDGES * 4;
    unsigned short* Xbf  = (unsigned short*)w; w += (size_t)N_NODES * HID * 2;
    unsigned short* H0bf = (unsigned short*)w; w += (size_t)N_NODES * HID * 2;
    unsigned short* Hbf  = (unsigned short*)w; w += (size_t)N_NODES * HID * 2;
    unsigned short* Wp   = (unsigned short*)w; w += (size_t)6 * 2048 * 8 * 2;
    float* bnpart = (float*)w; w += (size_t)MLP_BLOCKS * 256 * 4;   // 3.2 MB
    float* bnsum = (float*)w;  w += 2 * HID * 4;
    float* bnsc  = (float*)w;  w += 2 * HID * 4;
    float* g     = (float*)w;  w += (size_t)N_GRAPHS * HID * 4;

    hipMemsetAsync(deg, 0, (size_t)N_NODES * 4, stream);
    hipMemsetAsync(cursor, 0, (size_t)N_NODES * 4, stream);
    hipMemsetAsync(g, 0, (size_t)N_GRAPHS * HID * 4, stream);

    k_count<<<(N_EDGES + 255) / 256, 256, 0, stream>>>(dst, deg);
    k_scan1<<<NCHUNKS, 256, 0, stream>>>(deg, chunkSums);
    k_scan2<<<1, 64, 0, stream>>>(chunkSums, offs);
    k_scan3<<<NCHUNKS, 256, 0, stream>>>(deg, chunkSums, offs);
    k_fill<<<(N_EDGES + 255) / 256, 256, 0, stream>>>(src, dst, offs, cursor, srcSorted);
    k_packW<<<(6 * 2048 + 255) / 256, 256, 0, stream>>>(W1s, W2s, Wp);
    k_x2bf<<<(N_NODES * HID / 8 + 255) / 256, 256, 0, stream>>>(x, Xbf);

    const int aggBlocks = N_NODES / 4;   // 12500, exact
    for (int l = 0; l < 3; l++) {
        if (l == 0)
            k_agg<false><<<aggBlocks, 256, 0, stream>>>(Xbf, nullptr, offs, srcSorted, H0bf);
        else
            k_agg<true><<<aggBlocks, 256, 0, stream>>>(Hbf, bnsc, offs, srcSorted, H0bf);
        k_mlp<<<MLP_BLOCKS, 64, 0, stream>>>(
            H0bf, Wp + (size_t)(l * 2 + 0) * 16384, b1s + (size_t)l * HID,
            Wp + (size_t)(l * 2 + 1) * 16384, b2s + (size_t)l * HID, Hbf, bnpart);
        hipMemsetAsync(bnsum, 0, 2 * HID * 4, stream);
        k_bnred<<<64, 256, 0, stream>>>(bnpart, bnsum);
        k_bnscale<<<1, 128, 0, stream>>>(bnsum, gammas + (size_t)l * HID,
                                         betas + (size_t)l * HID, bnsc);
    }

    k_pool<<<(N_NODES + POOL_CHUNK - 1) / POOL_CHUNK, 256, 0, stream>>>(Hbf, bnsc, batch, g);
    k_final<<<(N_GRAPHS * OUTC + 255) / 256, 256, 0, stream>>>(g, Wlin, blin, out);
}

// Round 5
// 429.109 us; speedup vs baseline: 1.7524x; 1.0432x over previous
//
#include <hip/hip_runtime.h>

#define N_NODES 50000
#define N_EDGES 800000
#define HID 128
#define OUTC 10
#define N_GRAPHS 64
#define BN_EPS 1e-5f

#define SCAN_CHUNK 1024
#define NCHUNKS ((N_NODES + SCAN_CHUNK - 1) / SCAN_CHUNK)   // 49
#define MLP_BLOCKS (N_NODES / 16)                           // 3125, exact

typedef __attribute__((ext_vector_type(8))) short short8_t;
typedef __attribute__((ext_vector_type(4))) float f32x4;

__device__ __forceinline__ unsigned short f2bf(float f) {
    unsigned u = __float_as_uint(f);
    u += 0x7FFFu + ((u >> 16) & 1u);     // RNE
    return (unsigned short)(u >> 16);
}
__device__ __forceinline__ float bf2f(unsigned short s) {
    return __uint_as_float(((unsigned)s) << 16);
}
__device__ __forceinline__ float2 bfp2f(unsigned v) {
    float2 r;
    r.x = __uint_as_float(v << 16);
    r.y = __uint_as_float(v & 0xFFFF0000u);
    return r;
}

// ---------------- CSR build ----------------
// count + rank capture: rank[e] = position of edge e within its dst bucket
__global__ void k_count(const int* __restrict__ dst, int* __restrict__ deg,
                        int* __restrict__ rank) {
    int e = blockIdx.x * 256 + threadIdx.x;
    if (e < N_EDGES) rank[e] = atomicAdd(&deg[dst[e]], 1);
}

__global__ void k_scan1(const int* __restrict__ deg, int* __restrict__ chunkSums) {
    __shared__ int sh[256];
    int base = blockIdx.x * SCAN_CHUNK;
    int t = threadIdx.x;
    int s = 0;
#pragma unroll
    for (int i = 0; i < 4; i++) {
        int idx = base + t * 4 + i;
        if (idx < N_NODES) s += deg[idx];
    }
    sh[t] = s;
    __syncthreads();
    for (int off = 128; off > 0; off >>= 1) {
        if (t < off) sh[t] += sh[t + off];
        __syncthreads();
    }
    if (t == 0) chunkSums[blockIdx.x] = sh[0];
}

__global__ void k_scan2(int* chunkSums, int* offs) {
    if (threadIdx.x == 0) {
        int run = 0;
        for (int i = 0; i < NCHUNKS; i++) {
            int v = chunkSums[i];
            chunkSums[i] = run;
            run += v;
        }
        offs[N_NODES] = run;
    }
}

__global__ void k_scan3(const int* __restrict__ deg, const int* __restrict__ chunkSums,
                        int* __restrict__ offs) {
    __shared__ int sh[256];
    int base = blockIdx.x * SCAN_CHUNK;
    int t = threadIdx.x;
    int v[4];
    int s = 0;
#pragma unroll
    for (int i = 0; i < 4; i++) {
        int idx = base + t * 4 + i;
        v[i] = (idx < N_NODES) ? deg[idx] : 0;
        s += v[i];
    }
    sh[t] = s;
    __syncthreads();
    for (int off = 1; off < 256; off <<= 1) {
        int x = sh[t];
        if (t >= off) x += sh[t - off];
        __syncthreads();
        sh[t] = x;
        __syncthreads();
    }
    int excl = sh[t] - s;
    int run = chunkSums[blockIdx.x] + excl;
#pragma unroll
    for (int i = 0; i < 4; i++) {
        int idx = base + t * 4 + i;
        if (idx < N_NODES) offs[idx] = run;
        run += v[i];
    }
}

// pure scatter, no atomics
__global__ void k_fill(const int* __restrict__ src, const int* __restrict__ dst,
                       const int* __restrict__ offs, const int* __restrict__ rank,
                       int* __restrict__ srcSorted) {
    int e = blockIdx.x * 256 + threadIdx.x;
    if (e < N_EDGES) {
        srcSorted[offs[dst[e]] + rank[e]] = src[e];
    }
}

// ---------------- x (f32) -> bf16 ----------------
__global__ void k_x2bf(const float* __restrict__ x, unsigned short* __restrict__ xbf) {
    int idx = blockIdx.x * 256 + threadIdx.x;
    if (idx >= N_NODES * HID / 8) return;
    const float4* p = (const float4*)&x[(size_t)idx * 8];
    float4 a = p[0], b = p[1];
    short8_t o = { (short)f2bf(a.x), (short)f2bf(a.y), (short)f2bf(a.z), (short)f2bf(a.w),
                   (short)f2bf(b.x), (short)f2bf(b.y), (short)f2bf(b.z), (short)f2bf(b.w) };
    *(short8_t*)&xbf[(size_t)idx * 8] = o;
}

// ---------------- Weight pre-pack into MFMA B-fragment order ----------------
__global__ void k_packW(const float* __restrict__ W1s, const float* __restrict__ W2s,
                        unsigned short* __restrict__ Wp) {
    int idx = blockIdx.x * 256 + threadIdx.x;
    if (idx >= 6 * 2048) return;
    int mat = idx >> 11;
    int rem = idx & 2047;
    int lane = rem & 63;
    int ks = (rem >> 6) & 3;
    int nt = rem >> 8;
    int l = mat >> 1;
    const float* W = (mat & 1) ? (W2s + (size_t)l * HID * HID) : (W1s + (size_t)l * HID * HID);
    int n = nt * 16 + (lane & 15);
    int k0 = ks * 32 + (lane >> 4) * 8;
    short8_t o;
#pragma unroll
    for (int j = 0; j < 8; j++) o[j] = (short)f2bf(W[(size_t)(k0 + j) * HID + n]);
    *(short8_t*)&Wp[(size_t)idx * 8] = o;
}

// ---------------- Fused aggregation + MFMA MLP, one wave per 16-node tile ----------------
// agg: h0_i = t(x_i) + sum_{j->i} t(x_j),  t = BN? relu(v*s+b) : v  (BN from prev layer)
// then: h = (relu(h0 W1 + b1)) W2 + b2, stored bf16; BN partial sums to bnpart.
#define MPITCH 136   // bf16 elems; 272 B rows, 16B-aligned

template <bool BN>
__global__ __launch_bounds__(64) void k_aggmlp(const unsigned short* __restrict__ X,
                                               const float* __restrict__ sc,
                                               const int* __restrict__ offs,
                                               const int* __restrict__ srcSorted,
                                               const unsigned short* __restrict__ W1p,
                                               const float* __restrict__ b1,
                                               const unsigned short* __restrict__ W2p,
                                               const float* __restrict__ b2,
                                               unsigned short* __restrict__ hbf,
                                               float* __restrict__ bnpart) {
    __shared__ __align__(16) unsigned short As[16 * MPITCH];   // 4352 B

    int lane = threadIdx.x;
    int lrow = lane & 15;
    int quad = lane >> 4;
    int rowBase = blockIdx.x * 16;   // exact: 3125*16 = 50000
    int c = lane * 2;

    float s0 = 0.f, s1 = 0.f, t0 = 0.f, t1 = 0.f;
    if (BN) { s0 = sc[c]; s1 = sc[c + 1]; t0 = sc[HID + c]; t1 = sc[HID + c + 1]; }

    // ---- aggregate 16 nodes into As ----
    for (int n = 0; n < 16; n++) {
        int node = rowBase + n;
        float2 own = bfp2f(*(const unsigned*)&X[(size_t)node * HID + c]);
        float a0, a1;
        if (BN) { a0 = fmaxf(own.x * s0 + t0, 0.f); a1 = fmaxf(own.y * s1 + t1, 0.f); }
        else    { a0 = own.x; a1 = own.y; }

        int e0 = offs[node];
        int deg = offs[node + 1] - e0;

        for (int base = 0; base < deg; base += 64) {
            int cnt = deg - base; if (cnt > 64) cnt = 64;
            int ii = base + lane;
            int myidx = srcSorted[e0 + (ii < deg ? ii : deg - 1)];
            int j = 0;
            for (; j + 8 <= cnt; j += 8) {
                int i0 = __shfl(myidx, j + 0), i1 = __shfl(myidx, j + 1);
                int i2 = __shfl(myidx, j + 2), i3 = __shfl(myidx, j + 3);
                int i4 = __shfl(myidx, j + 4), i5 = __shfl(myidx, j + 5);
                int i6 = __shfl(myidx, j + 6), i7 = __shfl(myidx, j + 7);
                unsigned v0 = *(const unsigned*)&X[(size_t)i0 * HID + c];
                unsigned v1 = *(const unsigned*)&X[(size_t)i1 * HID + c];
                unsigned v2 = *(const unsigned*)&X[(size_t)i2 * HID + c];
                unsigned v3 = *(const unsigned*)&X[(size_t)i3 * HID + c];
                unsigned v4 = *(const unsigned*)&X[(size_t)i4 * HID + c];
                unsigned v5 = *(const unsigned*)&X[(size_t)i5 * HID + c];
                unsigned v6 = *(const unsigned*)&X[(size_t)i6 * HID + c];
                unsigned v7 = *(const unsigned*)&X[(size_t)i7 * HID + c];
                float2 f0 = bfp2f(v0), f1 = bfp2f(v1), f2 = bfp2f(v2), f3 = bfp2f(v3);
                float2 f4 = bfp2f(v4), f5 = bfp2f(v5), f6 = bfp2f(v6), f7 = bfp2f(v7);
                if (BN) {
                    a0 += fmaxf(f0.x * s0 + t0, 0.f); a1 += fmaxf(f0.y * s1 + t1, 0.f);
                    a0 += fmaxf(f1.x * s0 + t0, 0.f); a1 += fmaxf(f1.y * s1 + t1, 0.f);
                    a0 += fmaxf(f2.x * s0 + t0, 0.f); a1 += fmaxf(f2.y * s1 + t1, 0.f);
                    a0 += fmaxf(f3.x * s0 + t0, 0.f); a1 += fmaxf(f3.y * s1 + t1, 0.f);
                    a0 += fmaxf(f4.x * s0 + t0, 0.f); a1 += fmaxf(f4.y * s1 + t1, 0.f);
                    a0 += fmaxf(f5.x * s0 + t0, 0.f); a1 += fmaxf(f5.y * s1 + t1, 0.f);
                    a0 += fmaxf(f6.x * s0 + t0, 0.f); a1 += fmaxf(f6.y * s1 + t1, 0.f);
                    a0 += fmaxf(f7.x * s0 + t0, 0.f); a1 += fmaxf(f7.y * s1 + t1, 0.f);
                } else {
                    a0 += f0.x + f1.x + f2.x + f3.x + f4.x + f5.x + f6.x + f7.x;
                    a1 += f0.y + f1.y + f2.y + f3.y + f4.y + f5.y + f6.y + f7.y;
                }
            }
            for (; j < cnt; j++) {
                int i0 = __shfl(myidx, j);
                float2 f0 = bfp2f(*(const unsigned*)&X[(size_t)i0 * HID + c]);
                if (BN) {
                    a0 += fmaxf(f0.x * s0 + t0, 0.f); a1 += fmaxf(f0.y * s1 + t1, 0.f);
                } else {
                    a0 += f0.x; a1 += f0.y;
                }
            }
        }
        unsigned o = (unsigned)f2bf(a0) | ((unsigned)f2bf(a1) << 16);
        *(unsigned*)&As[n * MPITCH + c] = o;
    }
    __syncthreads();

    // ---- MLP ----
    f32x4 acc[8];
#pragma unroll
    for (int t = 0; t < 8; t++) acc[t] = (f32x4){ 0.f, 0.f, 0.f, 0.f };

    short8_t a0f = *(const short8_t*)&As[lrow * MPITCH + 0 * 32 + quad * 8];
    short8_t a1f = *(const short8_t*)&As[lrow * MPITCH + 1 * 32 + quad * 8];
    short8_t a2f = *(const short8_t*)&As[lrow * MPITCH + 2 * 32 + quad * 8];
    short8_t a3f = *(const short8_t*)&As[lrow * MPITCH + 3 * 32 + quad * 8];

#pragma unroll
    for (int t = 0; t < 8; t++) {
        short8_t b0 = *(const short8_t*)&W1p[(size_t)((t * 4 + 0) * 64 + lane) * 8];
        short8_t b1_ = *(const short8_t*)&W1p[(size_t)((t * 4 + 1) * 64 + lane) * 8];
        short8_t b2_ = *(const short8_t*)&W1p[(size_t)((t * 4 + 2) * 64 + lane) * 8];
        short8_t b3 = *(const short8_t*)&W1p[(size_t)((t * 4 + 3) * 64 + lane) * 8];
        acc[t] = __builtin_amdgcn_mfma_f32_16x16x32_bf16(a0f, b0, acc[t], 0, 0, 0);
        acc[t] = __builtin_amdgcn_mfma_f32_16x16x32_bf16(a1f, b1_, acc[t], 0, 0, 0);
        acc[t] = __builtin_amdgcn_mfma_f32_16x16x32_bf16(a2f, b2_, acc[t], 0, 0, 0);
        acc[t] = __builtin_amdgcn_mfma_f32_16x16x32_bf16(a3f, b3, acc[t], 0, 0, 0);
    }
    __syncthreads();

    // bias + relu, C-layout -> As
#pragma unroll
    for (int t = 0; t < 8; t++) {
        int col = t * 16 + lrow;
        float bb = b1[col];
#pragma unroll
        for (int r = 0; r < 4; r++) {
            float v = fmaxf(acc[t][r] + bb, 0.f);
            As[(quad * 4 + r) * MPITCH + col] = f2bf(v);
        }
    }
    __syncthreads();

    short8_t t0f = *(const short8_t*)&As[lrow * MPITCH + 0 * 32 + quad * 8];
    short8_t t1f = *(const short8_t*)&As[lrow * MPITCH + 1 * 32 + quad * 8];
    short8_t t2f = *(const short8_t*)&As[lrow * MPITCH + 2 * 32 + quad * 8];
    short8_t t3f = *(const short8_t*)&As[lrow * MPITCH + 3 * 32 + quad * 8];

#pragma unroll
    for (int t = 0; t < 8; t++) acc[t] = (f32x4){ 0.f, 0.f, 0.f, 0.f };

#pragma unroll
    for (int t = 0; t < 8; t++) {
        short8_t b0 = *(const short8_t*)&W2p[(size_t)((t * 4 + 0) * 64 + lane) * 8];
        short8_t b1_ = *(const short8_t*)&W2p[(size_t)((t * 4 + 1) * 64 + lane) * 8];
        short8_t b2_ = *(const short8_t*)&W2p[(size_t)((t * 4 + 2) * 64 + lane) * 8];
        short8_t b3 = *(const short8_t*)&W2p[(size_t)((t * 4 + 3) * 64 + lane) * 8];
        acc[t] = __builtin_amdgcn_mfma_f32_16x16x32_bf16(t0f, b0, acc[t], 0, 0, 0);
        acc[t] = __builtin_amdgcn_mfma_f32_16x16x32_bf16(t1f, b1_, acc[t], 0, 0, 0);
        acc[t] = __builtin_amdgcn_mfma_f32_16x16x32_bf16(t2f, b2_, acc[t], 0, 0, 0);
        acc[t] = __builtin_amdgcn_mfma_f32_16x16x32_bf16(t3f, b3, acc[t], 0, 0, 0);
    }
    __syncthreads();

    // bias + pack + BN sums (quad-reduced, no atomics)
    float s1v[8], s2v[8];
#pragma unroll
    for (int t = 0; t < 8; t++) {
        int col = t * 16 + lrow;
        float bb = b2[col];
        float p1 = 0.f, p2 = 0.f;
#pragma unroll
        for (int r = 0; r < 4; r++) {
            unsigned short bv = f2bf(acc[t][r] + bb);
            float vr = bf2f(bv);
            p1 += vr; p2 += vr * vr;
            As[(quad * 4 + r) * MPITCH + col] = bv;
        }
        p1 += __shfl_xor(p1, 16); p1 += __shfl_xor(p1, 32);
        p2 += __shfl_xor(p2, 16); p2 += __shfl_xor(p2, 32);
        s1v[t] = p1; s2v[t] = p2;
    }
    __syncthreads();

    unsigned short* Orow = hbf + (size_t)(rowBase + lrow) * HID;
#pragma unroll
    for (int cc = 0; cc < 4; cc++)
        *(short8_t*)&Orow[cc * 32 + quad * 8] = *(const short8_t*)&As[lrow * MPITCH + cc * 32 + quad * 8];

    if (quad == 0) {
        float* bp = bnpart + (size_t)blockIdx.x * 256;
#pragma unroll
        for (int t = 0; t < 8; t++) {
            bp[t * 16 + lrow] = s1v[t];
            bp[128 + t * 16 + lrow] = s2v[t];
        }
    }
}

// ---------------- BN partial reduce (no atomics, no memset) ----------------
__global__ void k_bnred(const float* __restrict__ bnpart, float* __restrict__ bnred2) {
    float acc = 0.f;
    for (int r = blockIdx.x; r < MLP_BLOCKS; r += 64)
        acc += bnpart[(size_t)r * 256 + threadIdx.x];
    bnred2[blockIdx.x * 256 + threadIdx.x] = acc;
}

// ---------------- BN final reduce + scale/shift ----------------
__global__ void k_bnscale(const float* __restrict__ bnred2, const float* __restrict__ gamma,
                          const float* __restrict__ beta, float* __restrict__ sc) {
    __shared__ float tot[256];
    int t = threadIdx.x;
    float a = 0.f;
    for (int j = 0; j < 64; j++) a += bnred2[j * 256 + t];
    tot[t] = a;
    __syncthreads();
    if (t < HID) {
        float mean = tot[t] * (1.0f / N_NODES);
        float var = tot[HID + t] * (1.0f / N_NODES) - mean * mean;
        float s = gamma[t] * rsqrtf(var + BN_EPS);
        sc[t] = s;
        sc[HID + t] = beta[t] - mean * s;
    }
}

// ---------------- Pool with fused BN+ReLU (batch sorted) ----------------
#define POOL_CHUNK 512
__global__ void k_pool(const unsigned short* __restrict__ X, const float* __restrict__ sc,
                       const int* __restrict__ batch, float* __restrict__ g) {
    int lane = threadIdx.x & 31;
    int rg = threadIdx.x >> 5;
    int c = lane * 4;
    float4 s = *(const float4*)&sc[c];
    float4 b = *(const float4*)&sc[HID + c];
    int base = blockIdx.x * POOL_CHUNK;
    int end = base + POOL_CHUNK;
    if (end > N_NODES) end = N_NODES;
    float a0 = 0.f, a1 = 0.f, a2 = 0.f, a3 = 0.f;
    int cur = -1;
    for (int r = base + rg; r < end; r += 8) {
        int bb = batch[r];
        if (bb != cur) {
            if (cur >= 0) {
                atomicAdd(&g[cur * HID + c + 0], a0);
                atomicAdd(&g[cur * HID + c + 1], a1);
                atomicAdd(&g[cur * HID + c + 2], a2);
                atomicAdd(&g[cur * HID + c + 3], a3);
            }
            cur = bb;
            a0 = a1 = a2 = a3 = 0.f;
        }
        ushort4 v = *(const ushort4*)&X[(size_t)r * HID + c];
        a0 += fmaxf(bf2f(v.x) * s.x + b.x, 0.f);
        a1 += fmaxf(bf2f(v.y) * s.y + b.y, 0.f);
        a2 += fmaxf(bf2f(v.z) * s.z + b.z, 0.f);
        a3 += fmaxf(bf2f(v.w) * s.w + b.w, 0.f);
    }
    if (cur >= 0) {
        atomicAdd(&g[cur * HID + c + 0], a0);
        atomicAdd(&g[cur * HID + c + 1], a1);
        atomicAdd(&g[cur * HID + c + 2], a2);
        atomicAdd(&g[cur * HID + c + 3], a3);
    }
}

// ---------------- Final linear ----------------
__global__ void k_final(const float* __restrict__ g, const float* __restrict__ Wlin,
                        const float* __restrict__ blin, float* __restrict__ out) {
    int o = blockIdx.x * 256 + threadIdx.x;
    if (o >= N_GRAPHS * OUTC) return;
    int gi = o / OUTC, c = o % OUTC;
    float s = blin[c];
    for (int k = 0; k < HID; k++) s += g[gi * HID + k] * Wlin[k * OUTC + c];
    out[o] = s;
}

// ---------------- Launch ----------------
extern "C" void kernel_launch(void* const* d_in, const int* in_sizes, int n_in,
                              void* d_out, int out_size, void* d_ws, size_t ws_size,
                              hipStream_t stream) {
    const float* x      = (const float*)d_in[0];
    const float* W1s    = (const float*)d_in[1];
    const float* b1s    = (const float*)d_in[2];
    const float* W2s    = (const float*)d_in[3];
    const float* b2s    = (const float*)d_in[4];
    const float* gammas = (const float*)d_in[5];
    const float* betas  = (const float*)d_in[6];
    const float* Wlin   = (const float*)d_in[7];
    const float* blin   = (const float*)d_in[8];
    const int* edge_index = (const int*)d_in[9];
    const int* batch    = (const int*)d_in[10];
    float* out = (float*)d_out;

    const int* src = edge_index;
    const int* dst = edge_index + N_EDGES;

    char* w = (char*)d_ws;
    int* deg       = (int*)w;  w += (size_t)N_NODES * 4;
    int* rank      = (int*)w;  w += (size_t)N_EDGES * 4;            // 3.2 MB
    int* offs      = (int*)w;  w += 200016;
    int* chunkSums = (int*)w;  w += 256;
    int* srcSorted = (int*)w;  w += (size_t)N_EDGES * 4;            // 3.2 MB
    unsigned short* Xbf = (unsigned short*)w; w += (size_t)N_NODES * HID * 2;   // 12.8 MB
    unsigned short* HA  = (unsigned short*)w; w += (size_t)N_NODES * HID * 2;
    unsigned short* HB  = (unsigned short*)w; w += (size_t)N_NODES * HID * 2;
    unsigned short* Wp  = (unsigned short*)w; w += (size_t)6 * 2048 * 8 * 2;
    float* bnpart = (float*)w; w += (size_t)MLP_BLOCKS * 256 * 4;   // 3.2 MB
    float* bnred2 = (float*)w; w += (size_t)64 * 256 * 4;
    float* bnsc   = (float*)w; w += 2 * HID * 4;
    float* g      = (float*)w; w += (size_t)N_GRAPHS * HID * 4;

    hipMemsetAsync(deg, 0, (size_t)N_NODES * 4, stream);
    hipMemsetAsync(g, 0, (size_t)N_GRAPHS * HID * 4, stream);

    k_count<<<(N_EDGES + 255) / 256, 256, 0, stream>>>(dst, deg, rank);
    k_scan1<<<NCHUNKS, 256, 0, stream>>>(deg, chunkSums);
    k_scan2<<<1, 64, 0, stream>>>(chunkSums, offs);
    k_scan3<<<NCHUNKS, 256, 0, stream>>>(deg, chunkSums, offs);
    k_fill<<<(N_EDGES + 255) / 256, 256, 0, stream>>>(src, dst, offs, rank, srcSorted);
    k_packW<<<(6 * 2048 + 255) / 256, 256, 0, stream>>>(W1s, W2s, Wp);
    k_x2bf<<<(N_NODES * HID / 8 + 255) / 256, 256, 0, stream>>>(x, Xbf);

    // layer 0: Xbf -> HA ; layer 1: HA -> HB ; layer 2: HB -> HA
    const unsigned short* in0 = Xbf;
    unsigned short* outs[3] = { HA, HB, HA };
    for (int l = 0; l < 3; l++) {
        const unsigned short* xin = (l == 0) ? in0 : outs[l - 1];
        if (l == 0)
            k_aggmlp<false><<<MLP_BLOCKS, 64, 0, stream>>>(
                xin, nullptr, offs, srcSorted,
                Wp + (size_t)(l * 2 + 0) * 16384, b1s + (size_t)l * HID,
                Wp + (size_t)(l * 2 + 1) * 16384, b2s + (size_t)l * HID, outs[l], bnpart);
        else
            k_aggmlp<true><<<MLP_BLOCKS, 64, 0, stream>>>(
                xin, bnsc, offs, srcSorted,
                Wp + (size_t)(l * 2 + 0) * 16384, b1s + (size_t)l * HID,
                Wp + (size_t)(l * 2 + 1) * 16384, b2s + (size_t)l * HID, outs[l], bnpart);
        k_bnred<<<64, 256, 0, stream>>>(bnpart, bnred2);
        k_bnscale<<<1, 256, 0, stream>>>(bnred2, gammas + (size_t)l * HID,
                                         betas + (size_t)l * HID, bnsc);
    }

    k_pool<<<(N_NODES + POOL_CHUNK - 1) / POOL_CHUNK, 256, 0, stream>>>(outs[2], bnsc, batch, g);
    k_final<<<(N_GRAPHS * OUTC + 255) / 256, 256, 0, stream>>>(g, Wlin, blin, out);
}

// Round 6
// 394.176 us; speedup vs baseline: 1.9077x; 1.0886x over previous
//
#include <hip/hip_runtime.h>

#define N_NODES 50000
#define N_EDGES 800000
#define HID 128
#define OUTC 10
#define N_GRAPHS 64
#define BN_EPS 1e-5f

#define SCAN_CHUNK 1024
#define NCHUNKS ((N_NODES + SCAN_CHUNK - 1) / SCAN_CHUNK)   // 49
#define MLP_BLOCKS (N_NODES / 16)                           // 3125, exact

typedef __attribute__((ext_vector_type(8))) short short8_t;
typedef __attribute__((ext_vector_type(4))) float f32x4;

__device__ __forceinline__ unsigned short f2bf(float f) {
    unsigned u = __float_as_uint(f);
    u += 0x7FFFu + ((u >> 16) & 1u);     // RNE
    return (unsigned short)(u >> 16);
}
__device__ __forceinline__ float bf2f(unsigned short s) {
    return __uint_as_float(((unsigned)s) << 16);
}
__device__ __forceinline__ float2 bfp2f(unsigned v) {
    float2 r;
    r.x = __uint_as_float(v << 16);
    r.y = __uint_as_float(v & 0xFFFF0000u);
    return r;
}

// ---------------- CSR build ----------------
__global__ void k_count(const int* __restrict__ dst, int* __restrict__ deg,
                        int* __restrict__ rank) {
    int e = blockIdx.x * 256 + threadIdx.x;
    if (e < N_EDGES) rank[e] = atomicAdd(&deg[dst[e]], 1);
}

__global__ void k_scan1(const int* __restrict__ deg, int* __restrict__ chunkSums) {
    __shared__ int sh[256];
    int base = blockIdx.x * SCAN_CHUNK;
    int t = threadIdx.x;
    int s = 0;
#pragma unroll
    for (int i = 0; i < 4; i++) {
        int idx = base + t * 4 + i;
        if (idx < N_NODES) s += deg[idx];
    }
    sh[t] = s;
    __syncthreads();
    for (int off = 128; off > 0; off >>= 1) {
        if (t < off) sh[t] += sh[t + off];
        __syncthreads();
    }
    if (t == 0) chunkSums[blockIdx.x] = sh[0];
}

// scan3 with per-block chunk prefix computed locally (scan2 eliminated)
__global__ void k_scan23(const int* __restrict__ deg, const int* __restrict__ chunkSums,
                         int* __restrict__ offs) {
    __shared__ int sh[256];
    __shared__ int chunkPrefix;
    int base = blockIdx.x * SCAN_CHUNK;
    int t = threadIdx.x;
    if (t == 0) {
        int r = 0;
        for (int i = 0; i < blockIdx.x; i++) r += chunkSums[i];
        chunkPrefix = r;
    }
    int v[4];
    int s = 0;
#pragma unroll
    for (int i = 0; i < 4; i++) {
        int idx = base + t * 4 + i;
        v[i] = (idx < N_NODES) ? deg[idx] : 0;
        s += v[i];
    }
    sh[t] = s;
    __syncthreads();
    for (int off = 1; off < 256; off <<= 1) {
        int x = sh[t];
        if (t >= off) x += sh[t - off];
        __syncthreads();
        sh[t] = x;
        __syncthreads();
    }
    int excl = sh[t] - s;
    int run = chunkPrefix + excl;
#pragma unroll
    for (int i = 0; i < 4; i++) {
        int idx = base + t * 4 + i;
        if (idx < N_NODES) offs[idx] = run;
        run += v[i];
    }
    if (blockIdx.x == NCHUNKS - 1 && t == 255) offs[N_NODES] = run;  // == N_EDGES
}

// pure scatter, no atomics
__global__ void k_fill(const int* __restrict__ src, const int* __restrict__ dst,
                       const int* __restrict__ offs, const int* __restrict__ rank,
                       int* __restrict__ srcSorted) {
    int e = blockIdx.x * 256 + threadIdx.x;
    if (e < N_EDGES) {
        srcSorted[offs[dst[e]] + rank[e]] = src[e];
    }
}

// ---------------- x (f32) -> bf16 ----------------
__global__ void k_x2bf(const float* __restrict__ x, unsigned short* __restrict__ xbf) {
    int idx = blockIdx.x * 256 + threadIdx.x;
    if (idx >= N_NODES * HID / 8) return;
    const float4* p = (const float4*)&x[(size_t)idx * 8];
    float4 a = p[0], b = p[1];
    short8_t o = { (short)f2bf(a.x), (short)f2bf(a.y), (short)f2bf(a.z), (short)f2bf(a.w),
                   (short)f2bf(b.x), (short)f2bf(b.y), (short)f2bf(b.z), (short)f2bf(b.w) };
    *(short8_t*)&xbf[(size_t)idx * 8] = o;
}

// ---------------- Weight pre-pack into MFMA B-fragment order ----------------
__global__ void k_packW(const float* __restrict__ W1s, const float* __restrict__ W2s,
                        unsigned short* __restrict__ Wp) {
    int idx = blockIdx.x * 256 + threadIdx.x;
    if (idx >= 6 * 2048) return;
    int mat = idx >> 11;
    int rem = idx & 2047;
    int lane = rem & 63;
    int ks = (rem >> 6) & 3;
    int nt = rem >> 8;
    int l = mat >> 1;
    const float* W = (mat & 1) ? (W2s + (size_t)l * HID * HID) : (W1s + (size_t)l * HID * HID);
    int n = nt * 16 + (lane & 15);
    int k0 = ks * 32 + (lane >> 4) * 8;
    short8_t o;
#pragma unroll
    for (int j = 0; j < 8; j++) o[j] = (short)f2bf(W[(size_t)(k0 + j) * HID + n]);
    *(short8_t*)&Wp[(size_t)idx * 8] = o;
}

// ---------------- Fused aggregation + MFMA MLP, one wave per 16-node tile ----------------
// Gather phase: each lane owns an 8-column slice (col0 = (lane&15)*8); 4 rows are
// fetched per dwordx4 instruction (quad = lane>>4 selects the row), accumulated in
// VGPRs, then quad-partials reduced via shfl_xor. No LDS staging.
#define MPITCH 136

template <bool BN>
__global__ __launch_bounds__(64) void k_aggmlp(const unsigned short* __restrict__ X,
                                               const float* __restrict__ sc,
                                               const int* __restrict__ offs,
                                               const int* __restrict__ srcSorted,
                                               const unsigned short* __restrict__ W1p,
                                               const float* __restrict__ b1,
                                               const unsigned short* __restrict__ W2p,
                                               const float* __restrict__ b2,
                                               unsigned short* __restrict__ hbf,
                                               float* __restrict__ bnpart) {
    __shared__ __align__(16) unsigned short As[16 * MPITCH];   // 4352 B

    int lane = threadIdx.x;
    int lrow = lane & 15;
    int quad = lane >> 4;
    int rowBase = blockIdx.x * 16;   // exact: 3125*16 = 50000
    int col0 = lrow * 8;

    float scv[8], shv[8];
    if (BN) {
#pragma unroll
        for (int j = 0; j < 8; j++) { scv[j] = sc[col0 + j]; shv[j] = sc[HID + col0 + j]; }
    }

    // ---- aggregate 16 nodes into As ----
    for (int n = 0; n < 16; n++) {
        int node = rowBase + n;
        float acc[8];
        {   // own row, counted by quad 0 only
            short8_t ov = *(const short8_t*)&X[(size_t)node * HID + col0];
            uint4 uu = *(uint4*)&ov;
            float2 p0 = bfp2f(uu.x), p1 = bfp2f(uu.y), p2 = bfp2f(uu.z), p3 = bfp2f(uu.w);
            float f[8] = { p0.x, p0.y, p1.x, p1.y, p2.x, p2.y, p3.x, p3.y };
#pragma unroll
            for (int j = 0; j < 8; j++) {
                float v = BN ? fmaxf(f[j] * scv[j] + shv[j], 0.f) : f[j];
                acc[j] = (quad == 0) ? v : 0.f;
            }
        }

        int e0 = offs[node];
        int deg = offs[node + 1] - e0;

        for (int base = 0; base < deg; base += 32) {
            int cnt = deg - base; if (cnt > 32) cnt = 32;
            int ipos = base + (lane & 31); if (ipos >= deg) ipos = deg - 1;
            int myidx = srcSorted[e0 + ipos];

            short8_t v[8];
#pragma unroll
            for (int u = 0; u < 8; u++) {
                int slot = u * 4 + quad;
                int sl = slot < cnt ? slot : cnt - 1;
                int ridx = __shfl(myidx, sl);
                v[u] = *(const short8_t*)&X[(size_t)ridx * HID + col0];
            }
#pragma unroll
            for (int u = 0; u < 8; u++) {
                int slot = u * 4 + quad;
                if (slot < cnt) {
                    uint4 uu = *(uint4*)&v[u];
                    float2 p0 = bfp2f(uu.x), p1 = bfp2f(uu.y), p2 = bfp2f(uu.z), p3 = bfp2f(uu.w);
                    float f[8] = { p0.x, p0.y, p1.x, p1.y, p2.x, p2.y, p3.x, p3.y };
#pragma unroll
                    for (int j = 0; j < 8; j++)
                        acc[j] += BN ? fmaxf(f[j] * scv[j] + shv[j], 0.f) : f[j];
                }
            }
        }

        // reduce quad partials
#pragma unroll
        for (int j = 0; j < 8; j++) {
            acc[j] += __shfl_xor(acc[j], 16);
            acc[j] += __shfl_xor(acc[j], 32);
        }
        if (quad == 0) {
            short8_t o;
#pragma unroll
            for (int j = 0; j < 8; j++) o[j] = (short)f2bf(acc[j]);
            *(short8_t*)&As[n * MPITCH + col0] = o;
        }
    }
    __syncthreads();

    // ---- MLP ----
    f32x4 acc[8];
#pragma unroll
    for (int t = 0; t < 8; t++) acc[t] = (f32x4){ 0.f, 0.f, 0.f, 0.f };

    short8_t a0f = *(const short8_t*)&As[lrow * MPITCH + 0 * 32 + quad * 8];
    short8_t a1f = *(const short8_t*)&As[lrow * MPITCH + 1 * 32 + quad * 8];
    short8_t a2f = *(const short8_t*)&As[lrow * MPITCH + 2 * 32 + quad * 8];
    short8_t a3f = *(const short8_t*)&As[lrow * MPITCH + 3 * 32 + quad * 8];

#pragma unroll
    for (int t = 0; t < 8; t++) {
        short8_t b0 = *(const short8_t*)&W1p[(size_t)((t * 4 + 0) * 64 + lane) * 8];
        short8_t b1_ = *(const short8_t*)&W1p[(size_t)((t * 4 + 1) * 64 + lane) * 8];
        short8_t b2_ = *(const short8_t*)&W1p[(size_t)((t * 4 + 2) * 64 + lane) * 8];
        short8_t b3 = *(const short8_t*)&W1p[(size_t)((t * 4 + 3) * 64 + lane) * 8];
        acc[t] = __builtin_amdgcn_mfma_f32_16x16x32_bf16(a0f, b0, acc[t], 0, 0, 0);
        acc[t] = __builtin_amdgcn_mfma_f32_16x16x32_bf16(a1f, b1_, acc[t], 0, 0, 0);
        acc[t] = __builtin_amdgcn_mfma_f32_16x16x32_bf16(a2f, b2_, acc[t], 0, 0, 0);
        acc[t] = __builtin_amdgcn_mfma_f32_16x16x32_bf16(a3f, b3, acc[t], 0, 0, 0);
    }
    __syncthreads();

    // bias + relu, C-layout -> As
#pragma unroll
    for (int t = 0; t < 8; t++) {
        int col = t * 16 + lrow;
        float bb = b1[col];
#pragma unroll
        for (int r = 0; r < 4; r++) {
            float v = fmaxf(acc[t][r] + bb, 0.f);
            As[(quad * 4 + r) * MPITCH + col] = f2bf(v);
        }
    }
    __syncthreads();

    short8_t t0f = *(const short8_t*)&As[lrow * MPITCH + 0 * 32 + quad * 8];
    short8_t t1f = *(const short8_t*)&As[lrow * MPITCH + 1 * 32 + quad * 8];
    short8_t t2f = *(const short8_t*)&As[lrow * MPITCH + 2 * 32 + quad * 8];
    short8_t t3f = *(const short8_t*)&As[lrow * MPITCH + 3 * 32 + quad * 8];

#pragma unroll
    for (int t = 0; t < 8; t++) acc[t] = (f32x4){ 0.f, 0.f, 0.f, 0.f };

#pragma unroll
    for (int t = 0; t < 8; t++) {
        short8_t b0 = *(const short8_t*)&W2p[(size_t)((t * 4 + 0) * 64 + lane) * 8];
        short8_t b1_ = *(const short8_t*)&W2p[(size_t)((t * 4 + 1) * 64 + lane) * 8];
        short8_t b2_ = *(const short8_t*)&W2p[(size_t)((t * 4 + 2) * 64 + lane) * 8];
        short8_t b3 = *(const short8_t*)&W2p[(size_t)((t * 4 + 3) * 64 + lane) * 8];
        acc[t] = __builtin_amdgcn_mfma_f32_16x16x32_bf16(t0f, b0, acc[t], 0, 0, 0);
        acc[t] = __builtin_amdgcn_mfma_f32_16x16x32_bf16(t1f, b1_, acc[t], 0, 0, 0);
        acc[t] = __builtin_amdgcn_mfma_f32_16x16x32_bf16(t2f, b2_, acc[t], 0, 0, 0);
        acc[t] = __builtin_amdgcn_mfma_f32_16x16x32_bf16(t3f, b3, acc[t], 0, 0, 0);
    }
    __syncthreads();

    // bias + pack + BN sums (quad-reduced, no atomics)
    float s1v[8], s2v[8];
#pragma unroll
    for (int t = 0; t < 8; t++) {
        int col = t * 16 + lrow;
        float bb = b2[col];
        float p1 = 0.f, p2 = 0.f;
#pragma unroll
        for (int r = 0; r < 4; r++) {
            unsigned short bv = f2bf(acc[t][r] + bb);
            float vr = bf2f(bv);
            p1 += vr; p2 += vr * vr;
            As[(quad * 4 + r) * MPITCH + col] = bv;
        }
        p1 += __shfl_xor(p1, 16); p1 += __shfl_xor(p1, 32);
        p2 += __shfl_xor(p2, 16); p2 += __shfl_xor(p2, 32);
        s1v[t] = p1; s2v[t] = p2;
    }
    __syncthreads();

    unsigned short* Orow = hbf + (size_t)(rowBase + lrow) * HID;
#pragma unroll
    for (int cc = 0; cc < 4; cc++)
        *(short8_t*)&Orow[cc * 32 + quad * 8] = *(const short8_t*)&As[lrow * MPITCH + cc * 32 + quad * 8];

    if (quad == 0) {
        float* bp = bnpart + (size_t)blockIdx.x * 256;
#pragma unroll
        for (int t = 0; t < 8; t++) {
            bp[t * 16 + lrow] = s1v[t];
            bp[128 + t * 16 + lrow] = s2v[t];
        }
    }
}

// ---------------- BN partial reduce (no atomics, no memset) ----------------
__global__ void k_bnred(const float* __restrict__ bnpart, float* __restrict__ bnred2) {
    float acc = 0.f;
    for (int r = blockIdx.x; r < MLP_BLOCKS; r += 64)
        acc += bnpart[(size_t)r * 256 + threadIdx.x];
    bnred2[blockIdx.x * 256 + threadIdx.x] = acc;
}

// ---------------- BN final reduce + scale/shift ----------------
__global__ void k_bnscale(const float* __restrict__ bnred2, const float* __restrict__ gamma,
                          const float* __restrict__ beta, float* __restrict__ sc) {
    __shared__ float tot[256];
    int t = threadIdx.x;
    float a = 0.f;
    for (int j = 0; j < 64; j++) a += bnred2[j * 256 + t];
    tot[t] = a;
    __syncthreads();
    if (t < HID) {
        float mean = tot[t] * (1.0f / N_NODES);
        float var = tot[HID + t] * (1.0f / N_NODES) - mean * mean;
        float s = gamma[t] * rsqrtf(var + BN_EPS);
        sc[t] = s;
        sc[HID + t] = beta[t] - mean * s;
    }
}

// ---------------- Pool with fused BN+ReLU (batch sorted) ----------------
#define POOL_CHUNK 512
__global__ void k_pool(const unsigned short* __restrict__ X, const float* __restrict__ sc,
                       const int* __restrict__ batch, float* __restrict__ g) {
    int lane = threadIdx.x & 31;
    int rg = threadIdx.x >> 5;
    int c = lane * 4;
    float4 s = *(const float4*)&sc[c];
    float4 b = *(const float4*)&sc[HID + c];
    int base = blockIdx.x * POOL_CHUNK;
    int end = base + POOL_CHUNK;
    if (end > N_NODES) end = N_NODES;
    float a0 = 0.f, a1 = 0.f, a2 = 0.f, a3 = 0.f;
    int cur = -1;
    for (int r = base + rg; r < end; r += 8) {
        int bb = batch[r];
        if (bb != cur) {
            if (cur >= 0) {
                atomicAdd(&g[cur * HID + c + 0], a0);
                atomicAdd(&g[cur * HID + c + 1], a1);
                atomicAdd(&g[cur * HID + c + 2], a2);
                atomicAdd(&g[cur * HID + c + 3], a3);
            }
            cur = bb;
            a0 = a1 = a2 = a3 = 0.f;
        }
        ushort4 v = *(const ushort4*)&X[(size_t)r * HID + c];
        a0 += fmaxf(bf2f(v.x) * s.x + b.x, 0.f);
        a1 += fmaxf(bf2f(v.y) * s.y + b.y, 0.f);
        a2 += fmaxf(bf2f(v.z) * s.z + b.z, 0.f);
        a3 += fmaxf(bf2f(v.w) * s.w + b.w, 0.f);
    }
    if (cur >= 0) {
        atomicAdd(&g[cur * HID + c + 0], a0);
        atomicAdd(&g[cur * HID + c + 1], a1);
        atomicAdd(&g[cur * HID + c + 2], a2);
        atomicAdd(&g[cur * HID + c + 3], a3);
    }
}

// ---------------- Final linear ----------------
__global__ void k_final(const float* __restrict__ g, const float* __restrict__ Wlin,
                        const float* __restrict__ blin, float* __restrict__ out) {
    int o = blockIdx.x * 256 + threadIdx.x;
    if (o >= N_GRAPHS * OUTC) return;
    int gi = o / OUTC, c = o % OUTC;
    float s = blin[c];
    for (int k = 0; k < HID; k++) s += g[gi * HID + k] * Wlin[k * OUTC + c];
    out[o] = s;
}

// ---------------- Launch ----------------
extern "C" void kernel_launch(void* const* d_in, const int* in_sizes, int n_in,
                              void* d_out, int out_size, void* d_ws, size_t ws_size,
                              hipStream_t stream) {
    const float* x      = (const float*)d_in[0];
    const float* W1s    = (const float*)d_in[1];
    const float* b1s    = (const float*)d_in[2];
    const float* W2s    = (const float*)d_in[3];
    const float* b2s    = (const float*)d_in[4];
    const float* gammas = (const float*)d_in[5];
    const float* betas  = (const float*)d_in[6];
    const float* Wlin   = (const float*)d_in[7];
    const float* blin   = (const float*)d_in[8];
    const int* edge_index = (const int*)d_in[9];
    const int* batch    = (const int*)d_in[10];
    float* out = (float*)d_out;

    const int* src = edge_index;
    const int* dst = edge_index + N_EDGES;

    char* w = (char*)d_ws;
    int* deg       = (int*)w;  w += (size_t)N_NODES * 4;
    int* rank      = (int*)w;  w += (size_t)N_EDGES * 4;
    int* offs      = (int*)w;  w += 200016;
    int* chunkSums = (int*)w;  w += 256;
    int* srcSorted = (int*)w;  w += (size_t)N_EDGES * 4;
    unsigned short* Xbf = (unsigned short*)w; w += (size_t)N_NODES * HID * 2;
    unsigned short* HA  = (unsigned short*)w; w += (size_t)N_NODES * HID * 2;
    unsigned short* HB  = (unsigned short*)w; w += (size_t)N_NODES * HID * 2;
    unsigned short* Wp  = (unsigned short*)w; w += (size_t)6 * 2048 * 8 * 2;
    float* bnpart = (float*)w; w += (size_t)MLP_BLOCKS * 256 * 4;
    float* bnred2 = (float*)w; w += (size_t)64 * 256 * 4;
    float* bnsc   = (float*)w; w += 2 * HID * 4;
    float* g      = (float*)w; w += (size_t)N_GRAPHS * HID * 4;

    hipMemsetAsync(deg, 0, (size_t)N_NODES * 4, stream);
    hipMemsetAsync(g, 0, (size_t)N_GRAPHS * HID * 4, stream);

    k_count<<<(N_EDGES + 255) / 256, 256, 0, stream>>>(dst, deg, rank);
    k_scan1<<<NCHUNKS, 256, 0, stream>>>(deg, chunkSums);
    k_scan23<<<NCHUNKS, 256, 0, stream>>>(deg, chunkSums, offs);
    k_fill<<<(N_EDGES + 255) / 256, 256, 0, stream>>>(src, dst, offs, rank, srcSorted);
    k_packW<<<(6 * 2048 + 255) / 256, 256, 0, stream>>>(W1s, W2s, Wp);
    k_x2bf<<<(N_NODES * HID / 8 + 255) / 256, 256, 0, stream>>>(x, Xbf);

    // layer 0: Xbf -> HA ; layer 1: HA -> HB ; layer 2: HB -> HA
    const unsigned short* in0 = Xbf;
    unsigned short* outs[3] = { HA, HB, HA };
    for (int l = 0; l < 3; l++) {
        const unsigned short* xin = (l == 0) ? in0 : outs[l - 1];
        if (l == 0)
            k_aggmlp<false><<<MLP_BLOCKS, 64, 0, stream>>>(
                xin, nullptr, offs, srcSorted,
                Wp + (size_t)(l * 2 + 0) * 16384, b1s + (size_t)l * HID,
                Wp + (size_t)(l * 2 + 1) * 16384, b2s + (size_t)l * HID, outs[l], bnpart);
        else
            k_aggmlp<true><<<MLP_BLOCKS, 64, 0, stream>>>(
                xin, bnsc, offs, srcSorted,
                Wp + (size_t)(l * 2 + 0) * 16384, b1s + (size_t)l * HID,
                Wp + (size_t)(l * 2 + 1) * 16384, b2s + (size_t)l * HID, outs[l], bnpart);
        k_bnred<<<64, 256, 0, stream>>>(bnpart, bnred2);
        k_bnscale<<<1, 256, 0, stream>>>(bnred2, gammas + (size_t)l * HID,
                                         betas + (size_t)l * HID, bnsc);
    }

    k_pool<<<(N_NODES + POOL_CHUNK - 1) / POOL_CHUNK, 256, 0, stream>>>(outs[2], bnsc, batch, g);
    k_final<<<(N_GRAPHS * OUTC + 255) / 256, 256, 0, stream>>>(g, Wlin, blin, out);
}

// Round 7
// 386.588 us; speedup vs baseline: 1.9452x; 1.0196x over previous
//
#include <hip/hip_runtime.h>

#define N_NODES 50000
#define N_EDGES 800000
#define HID 128
#define OUTC 10
#define N_GRAPHS 64
#define BN_EPS 1e-5f

#define SCAN_CHUNK 1024
#define NCHUNKS ((N_NODES + SCAN_CHUNK - 1) / SCAN_CHUNK)   // 49
#define MLP_BLOCKS (N_NODES / 16)                           // 3125, exact

typedef __attribute__((ext_vector_type(8))) short short8_t;
typedef __attribute__((ext_vector_type(4))) float f32x4;

__device__ __forceinline__ unsigned short f2bf(float f) {
    unsigned u = __float_as_uint(f);
    u += 0x7FFFu + ((u >> 16) & 1u);     // RNE
    return (unsigned short)(u >> 16);
}
__device__ __forceinline__ float bf2f(unsigned short s) {
    return __uint_as_float(((unsigned)s) << 16);
}
__device__ __forceinline__ float2 bfp2f(unsigned v) {
    float2 r;
    r.x = __uint_as_float(v << 16);
    r.y = __uint_as_float(v & 0xFFFF0000u);
    return r;
}

// ---------------- CSR build ----------------
__global__ void k_count(const int* __restrict__ dst, int* __restrict__ deg,
                        int* __restrict__ rank) {
    int e = blockIdx.x * 256 + threadIdx.x;
    if (e < N_EDGES) rank[e] = atomicAdd(&deg[dst[e]], 1);
}

__global__ void k_scan1(const int* __restrict__ deg, int* __restrict__ chunkSums) {
    __shared__ int sh[256];
    int base = blockIdx.x * SCAN_CHUNK;
    int t = threadIdx.x;
    int s = 0;
#pragma unroll
    for (int i = 0; i < 4; i++) {
        int idx = base + t * 4 + i;
        if (idx < N_NODES) s += deg[idx];
    }
    sh[t] = s;
    __syncthreads();
    for (int off = 128; off > 0; off >>= 1) {
        if (t < off) sh[t] += sh[t + off];
        __syncthreads();
    }
    if (t == 0) chunkSums[blockIdx.x] = sh[0];
}

__global__ void k_scan23(const int* __restrict__ deg, const int* __restrict__ chunkSums,
                         int* __restrict__ offs) {
    __shared__ int sh[256];
    __shared__ int chunkPrefix;
    int base = blockIdx.x * SCAN_CHUNK;
    int t = threadIdx.x;
    if (t == 0) {
        int r = 0;
        for (int i = 0; i < blockIdx.x; i++) r += chunkSums[i];
        chunkPrefix = r;
    }
    int v[4];
    int s = 0;
#pragma unroll
    for (int i = 0; i < 4; i++) {
        int idx = base + t * 4 + i;
        v[i] = (idx < N_NODES) ? deg[idx] : 0;
        s += v[i];
    }
    sh[t] = s;
    __syncthreads();
    for (int off = 1; off < 256; off <<= 1) {
        int x = sh[t];
        if (t >= off) x += sh[t - off];
        __syncthreads();
        sh[t] = x;
        __syncthreads();
    }
    int excl = sh[t] - s;
    int run = chunkPrefix + excl;
#pragma unroll
    for (int i = 0; i < 4; i++) {
        int idx = base + t * 4 + i;
        if (idx < N_NODES) offs[idx] = run;
        run += v[i];
    }
    if (blockIdx.x == NCHUNKS - 1 && t == 255) offs[N_NODES] = run;
}

__global__ void k_fill(const int* __restrict__ src, const int* __restrict__ dst,
                       const int* __restrict__ offs, const int* __restrict__ rank,
                       int* __restrict__ srcSorted) {
    int e = blockIdx.x * 256 + threadIdx.x;
    if (e < N_EDGES) {
        srcSorted[offs[dst[e]] + rank[e]] = src[e];
    }
}

// ---------------- prep: x->bf16 cast + weight pre-pack (merged) ----------------
#define X2BF_ITEMS (N_NODES * HID / 8)   // 800000
__global__ void k_prep(const float* __restrict__ x, const float* __restrict__ W1s,
                       const float* __restrict__ W2s,
                       unsigned short* __restrict__ xbf, unsigned short* __restrict__ Wp) {
    int gid = blockIdx.x * 256 + threadIdx.x;
    if (gid < X2BF_ITEMS) {
        const float4* p = (const float4*)&x[(size_t)gid * 8];
        float4 a = p[0], b = p[1];
        short8_t o = { (short)f2bf(a.x), (short)f2bf(a.y), (short)f2bf(a.z), (short)f2bf(a.w),
                       (short)f2bf(b.x), (short)f2bf(b.y), (short)f2bf(b.z), (short)f2bf(b.w) };
        *(short8_t*)&xbf[(size_t)gid * 8] = o;
    } else {
        int idx = gid - X2BF_ITEMS;
        if (idx >= 6 * 2048) return;
        int mat = idx >> 11;
        int rem = idx & 2047;
        int lane = rem & 63;
        int ks = (rem >> 6) & 3;
        int nt = rem >> 8;
        int l = mat >> 1;
        const float* W = (mat & 1) ? (W2s + (size_t)l * HID * HID) : (W1s + (size_t)l * HID * HID);
        int n = nt * 16 + (lane & 15);
        int k0 = ks * 32 + (lane >> 4) * 8;
        short8_t o;
#pragma unroll
        for (int j = 0; j < 8; j++) o[j] = (short)f2bf(W[(size_t)(k0 + j) * HID + n]);
        *(short8_t*)&Wp[(size_t)idx * 8] = o;
    }
}

// ---------------- Fused aggregation + MFMA MLP ----------------
// 256 threads = 4 waves per 16-node tile. Each wave gathers 4 nodes (4x memory
// concurrency vs 1-wave blocks). MLP: each wave computes 2 of 8 n-tiles per GEMM.
#define MPITCH 136

template <bool BN>
__global__ __launch_bounds__(256) void k_aggmlp(const unsigned short* __restrict__ X,
                                                const float* __restrict__ sc,
                                                const int* __restrict__ offs,
                                                const int* __restrict__ srcSorted,
                                                const unsigned short* __restrict__ W1p,
                                                const float* __restrict__ b1,
                                                const unsigned short* __restrict__ W2p,
                                                const float* __restrict__ b2,
                                                unsigned short* __restrict__ hbf,
                                                float* __restrict__ bnpart) {
    __shared__ __align__(16) unsigned short As[16 * MPITCH];   // 4352 B
    __shared__ __align__(16) unsigned short Ts[16 * MPITCH];   // 4352 B

    int tid = threadIdx.x;
    int wave = tid >> 6;
    int lane = tid & 63;
    int lrow = lane & 15;
    int quad = lane >> 4;
    int rowBase = blockIdx.x * 16;
    int col0 = lrow * 8;

    float scv[8], shv[8];
    if (BN) {
#pragma unroll
        for (int j = 0; j < 8; j++) { scv[j] = sc[col0 + j]; shv[j] = sc[HID + col0 + j]; }
    }

    // ---- gather: wave w handles nodes rowBase + w*4 .. +3 ----
    for (int ni = 0; ni < 4; ni++) {
        int tr = wave * 4 + ni;          // tile row 0..15
        int node = rowBase + tr;
        float acc[8];
        {
            short8_t ov = *(const short8_t*)&X[(size_t)node * HID + col0];
            uint4 uu = *(uint4*)&ov;
            float2 p0 = bfp2f(uu.x), p1 = bfp2f(uu.y), p2 = bfp2f(uu.z), p3 = bfp2f(uu.w);
            float f[8] = { p0.x, p0.y, p1.x, p1.y, p2.x, p2.y, p3.x, p3.y };
#pragma unroll
            for (int j = 0; j < 8; j++) {
                float v = BN ? fmaxf(f[j] * scv[j] + shv[j], 0.f) : f[j];
                acc[j] = (quad == 0) ? v : 0.f;
            }
        }

        int e0 = offs[node];
        int deg = offs[node + 1] - e0;

        for (int base = 0; base < deg; base += 32) {
            int cnt = deg - base; if (cnt > 32) cnt = 32;
            int ipos = base + (lane & 31); if (ipos >= deg) ipos = deg - 1;
            int myidx = srcSorted[e0 + ipos];

            short8_t v[8];
#pragma unroll
            for (int u = 0; u < 8; u++) {
                int slot = u * 4 + quad;
                int sl = slot < cnt ? slot : cnt - 1;
                int ridx = __shfl(myidx, sl);
                v[u] = *(const short8_t*)&X[(size_t)ridx * HID + col0];
            }
#pragma unroll
            for (int u = 0; u < 8; u++) {
                int slot = u * 4 + quad;
                if (slot < cnt) {
                    uint4 uu = *(uint4*)&v[u];
                    float2 p0 = bfp2f(uu.x), p1 = bfp2f(uu.y), p2 = bfp2f(uu.z), p3 = bfp2f(uu.w);
                    float f[8] = { p0.x, p0.y, p1.x, p1.y, p2.x, p2.y, p3.x, p3.y };
#pragma unroll
                    for (int j = 0; j < 8; j++)
                        acc[j] += BN ? fmaxf(f[j] * scv[j] + shv[j], 0.f) : f[j];
                }
            }
        }

#pragma unroll
        for (int j = 0; j < 8; j++) {
            acc[j] += __shfl_xor(acc[j], 16);
            acc[j] += __shfl_xor(acc[j], 32);
        }
        if (quad == 0) {
            short8_t o;
#pragma unroll
            for (int j = 0; j < 8; j++) o[j] = (short)f2bf(acc[j]);
            *(short8_t*)&As[tr * MPITCH + col0] = o;
        }
    }
    __syncthreads();   // bar A: As tile complete

    // ---- GEMM1: wave handles n-tiles {2*wave, 2*wave+1} ----
    int t0 = wave * 2;
    short8_t a0f = *(const short8_t*)&As[lrow * MPITCH + 0 * 32 + quad * 8];
    short8_t a1f = *(const short8_t*)&As[lrow * MPITCH + 1 * 32 + quad * 8];
    short8_t a2f = *(const short8_t*)&As[lrow * MPITCH + 2 * 32 + quad * 8];
    short8_t a3f = *(const short8_t*)&As[lrow * MPITCH + 3 * 32 + quad * 8];

    f32x4 acc1[2];
#pragma unroll
    for (int ti = 0; ti < 2; ti++) {
        int t = t0 + ti;
        f32x4 a = (f32x4){ 0.f, 0.f, 0.f, 0.f };
        short8_t b0 = *(const short8_t*)&W1p[(size_t)((t * 4 + 0) * 64 + lane) * 8];
        short8_t b1_ = *(const short8_t*)&W1p[(size_t)((t * 4 + 1) * 64 + lane) * 8];
        short8_t b2_ = *(const short8_t*)&W1p[(size_t)((t * 4 + 2) * 64 + lane) * 8];
        short8_t b3 = *(const short8_t*)&W1p[(size_t)((t * 4 + 3) * 64 + lane) * 8];
        a = __builtin_amdgcn_mfma_f32_16x16x32_bf16(a0f, b0, a, 0, 0, 0);
        a = __builtin_amdgcn_mfma_f32_16x16x32_bf16(a1f, b1_, a, 0, 0, 0);
        a = __builtin_amdgcn_mfma_f32_16x16x32_bf16(a2f, b2_, a, 0, 0, 0);
        a = __builtin_amdgcn_mfma_f32_16x16x32_bf16(a3f, b3, a, 0, 0, 0);
        acc1[ti] = a;
    }

    // bias + relu -> Ts (separate buffer; no hazard with As reads)
#pragma unroll
    for (int ti = 0; ti < 2; ti++) {
        int col = (t0 + ti) * 16 + lrow;
        float bb = b1[col];
#pragma unroll
        for (int r = 0; r < 4; r++) {
            float v = fmaxf(acc1[ti][r] + bb, 0.f);
            Ts[(quad * 4 + r) * MPITCH + col] = f2bf(v);
        }
    }
    __syncthreads();   // bar B: Ts complete (also: all GEMM1 As reads done)

    // ---- GEMM2 ----
    short8_t t0f = *(const short8_t*)&Ts[lrow * MPITCH + 0 * 32 + quad * 8];
    short8_t t1f = *(const short8_t*)&Ts[lrow * MPITCH + 1 * 32 + quad * 8];
    short8_t t2f = *(const short8_t*)&Ts[lrow * MPITCH + 2 * 32 + quad * 8];
    short8_t t3f = *(const short8_t*)&Ts[lrow * MPITCH + 3 * 32 + quad * 8];

    f32x4 acc2[2];
#pragma unroll
    for (int ti = 0; ti < 2; ti++) {
        int t = t0 + ti;
        f32x4 a = (f32x4){ 0.f, 0.f, 0.f, 0.f };
        short8_t b0 = *(const short8_t*)&W2p[(size_t)((t * 4 + 0) * 64 + lane) * 8];
        short8_t b1_ = *(const short8_t*)&W2p[(size_t)((t * 4 + 1) * 64 + lane) * 8];
        short8_t b2_ = *(const short8_t*)&W2p[(size_t)((t * 4 + 2) * 64 + lane) * 8];
        short8_t b3 = *(const short8_t*)&W2p[(size_t)((t * 4 + 3) * 64 + lane) * 8];
        a = __builtin_amdgcn_mfma_f32_16x16x32_bf16(t0f, b0, a, 0, 0, 0);
        a = __builtin_amdgcn_mfma_f32_16x16x32_bf16(t1f, b1_, a, 0, 0, 0);
        a = __builtin_amdgcn_mfma_f32_16x16x32_bf16(t2f, b2_, a, 0, 0, 0);
        a = __builtin_amdgcn_mfma_f32_16x16x32_bf16(t3f, b3, a, 0, 0, 0);
        acc2[ti] = a;
    }

    // bias + pack into As + BN partials (quad-reduced)
#pragma unroll
    for (int ti = 0; ti < 2; ti++) {
        int t = t0 + ti;
        int col = t * 16 + lrow;
        float bb = b2[col];
        float p1 = 0.f, p2 = 0.f;
#pragma unroll
        for (int r = 0; r < 4; r++) {
            unsigned short bv = f2bf(acc2[ti][r] + bb);
            float vr = bf2f(bv);
            p1 += vr; p2 += vr * vr;
            As[(quad * 4 + r) * MPITCH + col] = bv;
        }
        p1 += __shfl_xor(p1, 16); p1 += __shfl_xor(p1, 32);
        p2 += __shfl_xor(p2, 16); p2 += __shfl_xor(p2, 32);
        if (quad == 0) {
            float* bp = bnpart + (size_t)blockIdx.x * 256;
            bp[t * 16 + lrow] = p1;
            bp[128 + t * 16 + lrow] = p2;
        }
    }
    __syncthreads();   // bar C: C tile complete in As

    // coalesced store: 256 threads cover 16 rows x 16 chunks of 8
    {
        int r = tid >> 4;
        int c8 = (tid & 15) * 8;
        *(short8_t*)&hbf[(size_t)(rowBase + r) * HID + c8] =
            *(const short8_t*)&As[r * MPITCH + c8];
    }
}

// ---------------- BN partial reduce ----------------
__global__ void k_bnred(const float* __restrict__ bnpart, float* __restrict__ bnred2) {
    float acc = 0.f;
    for (int r = blockIdx.x; r < MLP_BLOCKS; r += 64)
        acc += bnpart[(size_t)r * 256 + threadIdx.x];
    bnred2[blockIdx.x * 256 + threadIdx.x] = acc;
}

// ---------------- BN final reduce + scale/shift ----------------
__global__ void k_bnscale(const float* __restrict__ bnred2, const float* __restrict__ gamma,
                          const float* __restrict__ beta, float* __restrict__ sc) {
    __shared__ float tot[256];
    int t = threadIdx.x;
    float a = 0.f;
    for (int j = 0; j < 64; j++) a += bnred2[j * 256 + t];
    tot[t] = a;
    __syncthreads();
    if (t < HID) {
        float mean = tot[t] * (1.0f / N_NODES);
        float var = tot[HID + t] * (1.0f / N_NODES) - mean * mean;
        float s = gamma[t] * rsqrtf(var + BN_EPS);
        sc[t] = s;
        sc[HID + t] = beta[t] - mean * s;
    }
}

// ---------------- Pool with fused BN+ReLU (batch sorted) ----------------
#define POOL_CHUNK 512
__global__ void k_pool(const unsigned short* __restrict__ X, const float* __restrict__ sc,
                       const int* __restrict__ batch, float* __restrict__ g) {
    int lane = threadIdx.x & 31;
    int rg = threadIdx.x >> 5;
    int c = lane * 4;
    float4 s = *(const float4*)&sc[c];
    float4 b = *(const float4*)&sc[HID + c];
    int base = blockIdx.x * POOL_CHUNK;
    int end = base + POOL_CHUNK;
    if (end > N_NODES) end = N_NODES;
    float a0 = 0.f, a1 = 0.f, a2 = 0.f, a3 = 0.f;
    int cur = -1;
    for (int r = base + rg; r < end; r += 8) {
        int bb = batch[r];
        if (bb != cur) {
            if (cur >= 0) {
                atomicAdd(&g[cur * HID + c + 0], a0);
                atomicAdd(&g[cur * HID + c + 1], a1);
                atomicAdd(&g[cur * HID + c + 2], a2);
                atomicAdd(&g[cur * HID + c + 3], a3);
            }
            cur = bb;
            a0 = a1 = a2 = a3 = 0.f;
        }
        ushort4 v = *(const ushort4*)&X[(size_t)r * HID + c];
        a0 += fmaxf(bf2f(v.x) * s.x + b.x, 0.f);
        a1 += fmaxf(bf2f(v.y) * s.y + b.y, 0.f);
        a2 += fmaxf(bf2f(v.z) * s.z + b.z, 0.f);
        a3 += fmaxf(bf2f(v.w) * s.w + b.w, 0.f);
    }
    if (cur >= 0) {
        atomicAdd(&g[cur * HID + c + 0], a0);
        atomicAdd(&g[cur * HID + c + 1], a1);
        atomicAdd(&g[cur * HID + c + 2], a2);
        atomicAdd(&g[cur * HID + c + 3], a3);
    }
}

// ---------------- Final linear ----------------
__global__ void k_final(const float* __restrict__ g, const float* __restrict__ Wlin,
                        const float* __restrict__ blin, float* __restrict__ out) {
    int o = blockIdx.x * 256 + threadIdx.x;
    if (o >= N_GRAPHS * OUTC) return;
    int gi = o / OUTC, c = o % OUTC;
    float s = blin[c];
    for (int k = 0; k < HID; k++) s += g[gi * HID + k] * Wlin[k * OUTC + c];
    out[o] = s;
}

// ---------------- Launch ----------------
extern "C" void kernel_launch(void* const* d_in, const int* in_sizes, int n_in,
                              void* d_out, int out_size, void* d_ws, size_t ws_size,
                              hipStream_t stream) {
    const float* x      = (const float*)d_in[0];
    const float* W1s    = (const float*)d_in[1];
    const float* b1s    = (const float*)d_in[2];
    const float* W2s    = (const float*)d_in[3];
    const float* b2s    = (const float*)d_in[4];
    const float* gammas = (const float*)d_in[5];
    const float* betas  = (const float*)d_in[6];
    const float* Wlin   = (const float*)d_in[7];
    const float* blin   = (const float*)d_in[8];
    const int* edge_index = (const int*)d_in[9];
    const int* batch    = (const int*)d_in[10];
    float* out = (float*)d_out;

    const int* src = edge_index;
    const int* dst = edge_index + N_EDGES;

    char* w = (char*)d_ws;
    int* deg       = (int*)w;  w += (size_t)N_NODES * 4;
    int* rank      = (int*)w;  w += (size_t)N_EDGES * 4;
    int* offs      = (int*)w;  w += 200016;
    int* chunkSums = (int*)w;  w += 256;
    int* srcSorted = (int*)w;  w += (size_t)N_EDGES * 4;
    unsigned short* Xbf = (unsigned short*)w; w += (size_t)N_NODES * HID * 2;
    unsigned short* HA  = (unsigned short*)w; w += (size_t)N_NODES * HID * 2;
    unsigned short* HB  = (unsigned short*)w; w += (size_t)N_NODES * HID * 2;
    unsigned short* Wp  = (unsigned short*)w; w += (size_t)6 * 2048 * 8 * 2;
    float* bnpart = (float*)w; w += (size_t)MLP_BLOCKS * 256 * 4;
    float* bnred2 = (float*)w; w += (size_t)64 * 256 * 4;
    float* bnsc   = (float*)w; w += 2 * HID * 4;
    float* g      = (float*)w; w += (size_t)N_GRAPHS * HID * 4;

    hipMemsetAsync(deg, 0, (size_t)N_NODES * 4, stream);
    hipMemsetAsync(g, 0, (size_t)N_GRAPHS * HID * 4, stream);

    k_count<<<(N_EDGES + 255) / 256, 256, 0, stream>>>(dst, deg, rank);
    k_scan1<<<NCHUNKS, 256, 0, stream>>>(deg, chunkSums);
    k_scan23<<<NCHUNKS, 256, 0, stream>>>(deg, chunkSums, offs);
    k_fill<<<(N_EDGES + 255) / 256, 256, 0, stream>>>(src, dst, offs, rank, srcSorted);
    k_prep<<<(X2BF_ITEMS + 6 * 2048 + 255) / 256, 256, 0, stream>>>(x, W1s, W2s, Xbf, Wp);

    // layer 0: Xbf -> HA ; layer 1: HA -> HB ; layer 2: HB -> HA
    const unsigned short* in0 = Xbf;
    unsigned short* outs[3] = { HA, HB, HA };
    for (int l = 0; l < 3; l++) {
        const unsigned short* xin = (l == 0) ? in0 : outs[l - 1];
        if (l == 0)
            k_aggmlp<false><<<MLP_BLOCKS, 256, 0, stream>>>(
                xin, nullptr, offs, srcSorted,
                Wp + (size_t)(l * 2 + 0) * 16384, b1s + (size_t)l * HID,
                Wp + (size_t)(l * 2 + 1) * 16384, b2s + (size_t)l * HID, outs[l], bnpart);
        else
            k_aggmlp<true><<<MLP_BLOCKS, 256, 0, stream>>>(
                xin, bnsc, offs, srcSorted,
                Wp + (size_t)(l * 2 + 0) * 16384, b1s + (size_t)l * HID,
                Wp + (size_t)(l * 2 + 1) * 16384, b2s + (size_t)l * HID, outs[l], bnpart);
        k_bnred<<<64, 256, 0, stream>>>(bnpart, bnred2);
        k_bnscale<<<1, 256, 0, stream>>>(bnred2, gammas + (size_t)l * HID,
                                         betas + (size_t)l * HID, bnsc);
    }

    k_pool<<<(N_NODES + POOL_CHUNK - 1) / POOL_CHUNK, 256, 0, stream>>>(outs[2], bnsc, batch, g);
    k_final<<<(N_GRAPHS * OUTC + 255) / 256, 256, 0, stream>>>(g, Wlin, blin, out);
}

// Round 8
// 380.919 us; speedup vs baseline: 1.9741x; 1.0149x over previous
//
#include <hip/hip_runtime.h>

#define N_NODES 50000
#define N_EDGES 800000
#define HID 128
#define OUTC 10
#define N_GRAPHS 64
#define BN_EPS 1e-5f

#define SCAN_CHUNK 1024
#define NCHUNKS ((N_NODES + SCAN_CHUNK - 1) / SCAN_CHUNK)   // 49
#define MLP_BLOCKS (N_NODES / 16)                           // 3125, exact

typedef __attribute__((ext_vector_type(8))) short short8_t;
typedef __attribute__((ext_vector_type(4))) float f32x4;

__device__ __forceinline__ unsigned short f2bf(float f) {
    unsigned u = __float_as_uint(f);
    u += 0x7FFFu + ((u >> 16) & 1u);     // RNE
    return (unsigned short)(u >> 16);
}
__device__ __forceinline__ float bf2f(unsigned short s) {
    return __uint_as_float(((unsigned)s) << 16);
}
__device__ __forceinline__ float2 bfp2f(unsigned v) {
    float2 r;
    r.x = __uint_as_float(v << 16);
    r.y = __uint_as_float(v & 0xFFFF0000u);
    return r;
}

// ---------------- CSR build ----------------
__global__ void k_count(const int* __restrict__ dst, int* __restrict__ deg,
                        int* __restrict__ rank) {
    int e = blockIdx.x * 256 + threadIdx.x;
    if (e < N_EDGES) rank[e] = atomicAdd(&deg[dst[e]], 1);
}

__global__ void k_scan1(const int* __restrict__ deg, int* __restrict__ chunkSums) {
    __shared__ int sh[256];
    int base = blockIdx.x * SCAN_CHUNK;
    int t = threadIdx.x;
    int s = 0;
#pragma unroll
    for (int i = 0; i < 4; i++) {
        int idx = base + t * 4 + i;
        if (idx < N_NODES) s += deg[idx];
    }
    sh[t] = s;
    __syncthreads();
    for (int off = 128; off > 0; off >>= 1) {
        if (t < off) sh[t] += sh[t + off];
        __syncthreads();
    }
    if (t == 0) chunkSums[blockIdx.x] = sh[0];
}

__global__ void k_scan23(const int* __restrict__ deg, const int* __restrict__ chunkSums,
                         int* __restrict__ offs) {
    __shared__ int sh[256];
    __shared__ int chunkPrefix;
    int base = blockIdx.x * SCAN_CHUNK;
    int t = threadIdx.x;
    if (t == 0) {
        int r = 0;
        for (int i = 0; i < blockIdx.x; i++) r += chunkSums[i];
        chunkPrefix = r;
    }
    int v[4];
    int s = 0;
#pragma unroll
    for (int i = 0; i < 4; i++) {
        int idx = base + t * 4 + i;
        v[i] = (idx < N_NODES) ? deg[idx] : 0;
        s += v[i];
    }
    sh[t] = s;
    __syncthreads();
    for (int off = 1; off < 256; off <<= 1) {
        int x = sh[t];
        if (t >= off) x += sh[t - off];
        __syncthreads();
        sh[t] = x;
        __syncthreads();
    }
    int excl = sh[t] - s;
    int run = chunkPrefix + excl;
#pragma unroll
    for (int i = 0; i < 4; i++) {
        int idx = base + t * 4 + i;
        if (idx < N_NODES) offs[idx] = run;
        run += v[i];
    }
    if (blockIdx.x == NCHUNKS - 1 && t == 255) offs[N_NODES] = run;
}

__global__ void k_fill(const int* __restrict__ src, const int* __restrict__ dst,
                       const int* __restrict__ offs, const int* __restrict__ rank,
                       int* __restrict__ srcSorted) {
    int e = blockIdx.x * 256 + threadIdx.x;
    if (e < N_EDGES) {
        srcSorted[offs[dst[e]] + rank[e]] = src[e];
    }
}

// ---------------- prep: x->bf16 cast + weight pre-pack (merged) ----------------
#define X2BF_ITEMS (N_NODES * HID / 8)   // 800000
__global__ void k_prep(const float* __restrict__ x, const float* __restrict__ W1s,
                       const float* __restrict__ W2s,
                       unsigned short* __restrict__ xbf, unsigned short* __restrict__ Wp) {
    int gid = blockIdx.x * 256 + threadIdx.x;
    if (gid < X2BF_ITEMS) {
        const float4* p = (const float4*)&x[(size_t)gid * 8];
        float4 a = p[0], b = p[1];
        short8_t o = { (short)f2bf(a.x), (short)f2bf(a.y), (short)f2bf(a.z), (short)f2bf(a.w),
                       (short)f2bf(b.x), (short)f2bf(b.y), (short)f2bf(b.z), (short)f2bf(b.w) };
        *(short8_t*)&xbf[(size_t)gid * 8] = o;
    } else {
        int idx = gid - X2BF_ITEMS;
        if (idx >= 6 * 2048) return;
        int mat = idx >> 11;
        int rem = idx & 2047;
        int lane = rem & 63;
        int ks = (rem >> 6) & 3;
        int nt = rem >> 8;
        int l = mat >> 1;
        const float* W = (mat & 1) ? (W2s + (size_t)l * HID * HID) : (W1s + (size_t)l * HID * HID);
        int n = nt * 16 + (lane & 15);
        int k0 = ks * 32 + (lane >> 4) * 8;
        short8_t o;
#pragma unroll
        for (int j = 0; j < 8; j++) o[j] = (short)f2bf(W[(size_t)(k0 + j) * HID + n]);
        *(short8_t*)&Wp[(size_t)idx * 8] = o;
    }
}

// ---------------- Fused aggregation + MFMA MLP ----------------
// 256 threads = 4 waves per 16-node tile. Gather: HALF-WAVE per node (16 col-slices
// x 2 row-slots), 16 edge-slots per chunk (matched to avg deg 16); a wave runs
// 2 pair-rounds with 2 independent latency chains each. MLP: wave computes 2 of
// 8 n-tiles per GEMM.
#define MPITCH 136

template <bool BN>
__global__ __launch_bounds__(256) void k_aggmlp(const unsigned short* __restrict__ X,
                                                const float* __restrict__ sc,
                                                const int* __restrict__ offs,
                                                const int* __restrict__ srcSorted,
                                                const unsigned short* __restrict__ W1p,
                                                const float* __restrict__ b1,
                                                const unsigned short* __restrict__ W2p,
                                                const float* __restrict__ b2,
                                                unsigned short* __restrict__ hbf,
                                                float* __restrict__ bnpart) {
    __shared__ __align__(16) unsigned short As[16 * MPITCH];   // 4352 B
    __shared__ __align__(16) unsigned short Ts[16 * MPITCH];   // 4352 B

    int tid = threadIdx.x;
    int wave = tid >> 6;
    int lane = tid & 63;
    int lrow = lane & 15;
    int quad = lane >> 4;
    int half = lane >> 5;        // which node of the pair
    int hl = lane & 31;          // lane within half
    int hq = hl >> 4;            // row-slot parity within half
    int rowBase = blockIdx.x * 16;
    int col0 = lrow * 8;         // (hl&15)*8 == (lane&15)*8

    float scv[8], shv[8];
    if (BN) {
#pragma unroll
        for (int j = 0; j < 8; j++) { scv[j] = sc[col0 + j]; shv[j] = sc[HID + col0 + j]; }
    }

    // ---- gather: 2 pair-rounds; each half-wave gathers one node ----
    for (int pr = 0; pr < 2; pr++) {
        int tr = wave * 4 + pr * 2 + half;   // tile row 0..15
        int node = rowBase + tr;
        float acc[8];
        {
            short8_t ov = *(const short8_t*)&X[(size_t)node * HID + col0];
            uint4 uu = *(uint4*)&ov;
            float2 p0 = bfp2f(uu.x), p1 = bfp2f(uu.y), p2 = bfp2f(uu.z), p3 = bfp2f(uu.w);
            float f[8] = { p0.x, p0.y, p1.x, p1.y, p2.x, p2.y, p3.x, p3.y };
#pragma unroll
            for (int j = 0; j < 8; j++) {
                float v = BN ? fmaxf(f[j] * scv[j] + shv[j], 0.f) : f[j];
                acc[j] = (hq == 0) ? v : 0.f;
            }
        }

        int e0 = offs[node];
        int deg = offs[node + 1] - e0;

        for (int base = 0; base < deg; base += 16) {
            int cnt = deg - base; if (cnt > 16) cnt = 16;
            int ipos = base + (hl & 15); if (ipos >= deg) ipos = deg - 1;
            int myidx = srcSorted[e0 + ipos];

            short8_t v[8];
#pragma unroll
            for (int u = 0; u < 8; u++) {
                int slot = u * 2 + hq;              // 0..15
                int sl = slot < cnt ? slot : cnt - 1;
                int ridx = __shfl(myidx, (half << 5) + sl);
                v[u] = *(const short8_t*)&X[(size_t)ridx * HID + col0];
            }
#pragma unroll
            for (int u = 0; u < 8; u++) {
                int slot = u * 2 + hq;
                if (slot < cnt) {
                    uint4 uu = *(uint4*)&v[u];
                    float2 p0 = bfp2f(uu.x), p1 = bfp2f(uu.y), p2 = bfp2f(uu.z), p3 = bfp2f(uu.w);
                    float f[8] = { p0.x, p0.y, p1.x, p1.y, p2.x, p2.y, p3.x, p3.y };
#pragma unroll
                    for (int j = 0; j < 8; j++)
                        acc[j] += BN ? fmaxf(f[j] * scv[j] + shv[j], 0.f) : f[j];
                }
            }
        }

        // combine the two row-slot partials within the half
#pragma unroll
        for (int j = 0; j < 8; j++) acc[j] += __shfl_xor(acc[j], 16);
        if (hq == 0) {
            short8_t o;
#pragma unroll
            for (int j = 0; j < 8; j++) o[j] = (short)f2bf(acc[j]);
            *(short8_t*)&As[tr * MPITCH + col0] = o;
        }
    }
    __syncthreads();   // bar A: As tile complete

    // ---- GEMM1: wave handles n-tiles {2*wave, 2*wave+1} ----
    int t0 = wave * 2;
    short8_t a0f = *(const short8_t*)&As[lrow * MPITCH + 0 * 32 + quad * 8];
    short8_t a1f = *(const short8_t*)&As[lrow * MPITCH + 1 * 32 + quad * 8];
    short8_t a2f = *(const short8_t*)&As[lrow * MPITCH + 2 * 32 + quad * 8];
    short8_t a3f = *(const short8_t*)&As[lrow * MPITCH + 3 * 32 + quad * 8];

    f32x4 acc1[2];
#pragma unroll
    for (int ti = 0; ti < 2; ti++) {
        int t = t0 + ti;
        f32x4 a = (f32x4){ 0.f, 0.f, 0.f, 0.f };
        short8_t b0 = *(const short8_t*)&W1p[(size_t)((t * 4 + 0) * 64 + lane) * 8];
        short8_t b1_ = *(const short8_t*)&W1p[(size_t)((t * 4 + 1) * 64 + lane) * 8];
        short8_t b2_ = *(const short8_t*)&W1p[(size_t)((t * 4 + 2) * 64 + lane) * 8];
        short8_t b3 = *(const short8_t*)&W1p[(size_t)((t * 4 + 3) * 64 + lane) * 8];
        a = __builtin_amdgcn_mfma_f32_16x16x32_bf16(a0f, b0, a, 0, 0, 0);
        a = __builtin_amdgcn_mfma_f32_16x16x32_bf16(a1f, b1_, a, 0, 0, 0);
        a = __builtin_amdgcn_mfma_f32_16x16x32_bf16(a2f, b2_, a, 0, 0, 0);
        a = __builtin_amdgcn_mfma_f32_16x16x32_bf16(a3f, b3, a, 0, 0, 0);
        acc1[ti] = a;
    }

    // bias + relu -> Ts
#pragma unroll
    for (int ti = 0; ti < 2; ti++) {
        int col = (t0 + ti) * 16 + lrow;
        float bb = b1[col];
#pragma unroll
        for (int r = 0; r < 4; r++) {
            float v = fmaxf(acc1[ti][r] + bb, 0.f);
            Ts[(quad * 4 + r) * MPITCH + col] = f2bf(v);
        }
    }
    __syncthreads();   // bar B: Ts complete

    // ---- GEMM2 ----
    short8_t t0f = *(const short8_t*)&Ts[lrow * MPITCH + 0 * 32 + quad * 8];
    short8_t t1f = *(const short8_t*)&Ts[lrow * MPITCH + 1 * 32 + quad * 8];
    short8_t t2f = *(const short8_t*)&Ts[lrow * MPITCH + 2 * 32 + quad * 8];
    short8_t t3f = *(const short8_t*)&Ts[lrow * MPITCH + 3 * 32 + quad * 8];

    f32x4 acc2[2];
#pragma unroll
    for (int ti = 0; ti < 2; ti++) {
        int t = t0 + ti;
        f32x4 a = (f32x4){ 0.f, 0.f, 0.f, 0.f };
        short8_t b0 = *(const short8_t*)&W2p[(size_t)((t * 4 + 0) * 64 + lane) * 8];
        short8_t b1_ = *(const short8_t*)&W2p[(size_t)((t * 4 + 1) * 64 + lane) * 8];
        short8_t b2_ = *(const short8_t*)&W2p[(size_t)((t * 4 + 2) * 64 + lane) * 8];
        short8_t b3 = *(const short8_t*)&W2p[(size_t)((t * 4 + 3) * 64 + lane) * 8];
        a = __builtin_amdgcn_mfma_f32_16x16x32_bf16(t0f, b0, a, 0, 0, 0);
        a = __builtin_amdgcn_mfma_f32_16x16x32_bf16(t1f, b1_, a, 0, 0, 0);
        a = __builtin_amdgcn_mfma_f32_16x16x32_bf16(t2f, b2_, a, 0, 0, 0);
        a = __builtin_amdgcn_mfma_f32_16x16x32_bf16(t3f, b3, a, 0, 0, 0);
        acc2[ti] = a;
    }

    // bias + pack into As + BN partials (quad-reduced)
#pragma unroll
    for (int ti = 0; ti < 2; ti++) {
        int t = t0 + ti;
        int col = t * 16 + lrow;
        float bb = b2[col];
        float p1 = 0.f, p2 = 0.f;
#pragma unroll
        for (int r = 0; r < 4; r++) {
            unsigned short bv = f2bf(acc2[ti][r] + bb);
            float vr = bf2f(bv);
            p1 += vr; p2 += vr * vr;
            As[(quad * 4 + r) * MPITCH + col] = bv;
        }
        p1 += __shfl_xor(p1, 16); p1 += __shfl_xor(p1, 32);
        p2 += __shfl_xor(p2, 16); p2 += __shfl_xor(p2, 32);
        if (quad == 0) {
            float* bp = bnpart + (size_t)blockIdx.x * 256;
            bp[t * 16 + lrow] = p1;
            bp[128 + t * 16 + lrow] = p2;
        }
    }
    __syncthreads();   // bar C: C tile complete in As

    // coalesced store: 256 threads cover 16 rows x 16 chunks of 8
    {
        int r = tid >> 4;
        int c8 = (tid & 15) * 8;
        *(short8_t*)&hbf[(size_t)(rowBase + r) * HID + c8] =
            *(const short8_t*)&As[r * MPITCH + c8];
    }
}

// ---------------- BN partial reduce ----------------
__global__ void k_bnred(const float* __restrict__ bnpart, float* __restrict__ bnred2) {
    float acc = 0.f;
    for (int r = blockIdx.x; r < MLP_BLOCKS; r += 64)
        acc += bnpart[(size_t)r * 256 + threadIdx.x];
    bnred2[blockIdx.x * 256 + threadIdx.x] = acc;
}

// ---------------- BN final reduce + scale/shift ----------------
__global__ void k_bnscale(const float* __restrict__ bnred2, const float* __restrict__ gamma,
                          const float* __restrict__ beta, float* __restrict__ sc) {
    __shared__ float tot[256];
    int t = threadIdx.x;
    float a = 0.f;
    for (int j = 0; j < 64; j++) a += bnred2[j * 256 + t];
    tot[t] = a;
    __syncthreads();
    if (t < HID) {
        float mean = tot[t] * (1.0f / N_NODES);
        float var = tot[HID + t] * (1.0f / N_NODES) - mean * mean;
        float s = gamma[t] * rsqrtf(var + BN_EPS);
        sc[t] = s;
        sc[HID + t] = beta[t] - mean * s;
    }
}

// ---------------- Pool with fused BN+ReLU (batch sorted) ----------------
#define POOL_CHUNK 512
__global__ void k_pool(const unsigned short* __restrict__ X, const float* __restrict__ sc,
                       const int* __restrict__ batch, float* __restrict__ g) {
    int lane = threadIdx.x & 31;
    int rg = threadIdx.x >> 5;
    int c = lane * 4;
    float4 s = *(const float4*)&sc[c];
    float4 b = *(const float4*)&sc[HID + c];
    int base = blockIdx.x * POOL_CHUNK;
    int end = base + POOL_CHUNK;
    if (end > N_NODES) end = N_NODES;
    float a0 = 0.f, a1 = 0.f, a2 = 0.f, a3 = 0.f;
    int cur = -1;
    for (int r = base + rg; r < end; r += 8) {
        int bb = batch[r];
        if (bb != cur) {
            if (cur >= 0) {
                atomicAdd(&g[cur * HID + c + 0], a0);
                atomicAdd(&g[cur * HID + c + 1], a1);
                atomicAdd(&g[cur * HID + c + 2], a2);
                atomicAdd(&g[cur * HID + c + 3], a3);
            }
            cur = bb;
            a0 = a1 = a2 = a3 = 0.f;
        }
        ushort4 v = *(const ushort4*)&X[(size_t)r * HID + c];
        a0 += fmaxf(bf2f(v.x) * s.x + b.x, 0.f);
        a1 += fmaxf(bf2f(v.y) * s.y + b.y, 0.f);
        a2 += fmaxf(bf2f(v.z) * s.z + b.z, 0.f);
        a3 += fmaxf(bf2f(v.w) * s.w + b.w, 0.f);
    }
    if (cur >= 0) {
        atomicAdd(&g[cur * HID + c + 0], a0);
        atomicAdd(&g[cur * HID + c + 1], a1);
        atomicAdd(&g[cur * HID + c + 2], a2);
        atomicAdd(&g[cur * HID + c + 3], a3);
    }
}

// ---------------- Final linear ----------------
__global__ void k_final(const float* __restrict__ g, const float* __restrict__ Wlin,
                        const float* __restrict__ blin, float* __restrict__ out) {
    int o = blockIdx.x * 256 + threadIdx.x;
    if (o >= N_GRAPHS * OUTC) return;
    int gi = o / OUTC, c = o % OUTC;
    float s = blin[c];
    for (int k = 0; k < HID; k++) s += g[gi * HID + k] * Wlin[k * OUTC + c];
    out[o] = s;
}

// ---------------- Launch ----------------
extern "C" void kernel_launch(void* const* d_in, const int* in_sizes, int n_in,
                              void* d_out, int out_size, void* d_ws, size_t ws_size,
                              hipStream_t stream) {
    const float* x      = (const float*)d_in[0];
    const float* W1s    = (const float*)d_in[1];
    const float* b1s    = (const float*)d_in[2];
    const float* W2s    = (const float*)d_in[3];
    const float* b2s    = (const float*)d_in[4];
    const float* gammas = (const float*)d_in[5];
    const float* betas  = (const float*)d_in[6];
    const float* Wlin   = (const float*)d_in[7];
    const float* blin   = (const float*)d_in[8];
    const int* edge_index = (const int*)d_in[9];
    const int* batch    = (const int*)d_in[10];
    float* out = (float*)d_out;

    const int* src = edge_index;
    const int* dst = edge_index + N_EDGES;

    char* w = (char*)d_ws;
    int* deg       = (int*)w;  w += (size_t)N_NODES * 4;
    int* rank      = (int*)w;  w += (size_t)N_EDGES * 4;
    int* offs      = (int*)w;  w += 200016;
    int* chunkSums = (int*)w;  w += 256;
    int* srcSorted = (int*)w;  w += (size_t)N_EDGES * 4;
    unsigned short* Xbf = (unsigned short*)w; w += (size_t)N_NODES * HID * 2;
    unsigned short* HA  = (unsigned short*)w; w += (size_t)N_NODES * HID * 2;
    unsigned short* HB  = (unsigned short*)w; w += (size_t)N_NODES * HID * 2;
    unsigned short* Wp  = (unsigned short*)w; w += (size_t)6 * 2048 * 8 * 2;
    float* bnpart = (float*)w; w += (size_t)MLP_BLOCKS * 256 * 4;
    float* bnred2 = (float*)w; w += (size_t)64 * 256 * 4;
    float* bnsc   = (float*)w; w += 2 * HID * 4;
    float* g      = (float*)w; w += (size_t)N_GRAPHS * HID * 4;

    hipMemsetAsync(deg, 0, (size_t)N_NODES * 4, stream);
    hipMemsetAsync(g, 0, (size_t)N_GRAPHS * HID * 4, stream);

    k_count<<<(N_EDGES + 255) / 256, 256, 0, stream>>>(dst, deg, rank);
    k_scan1<<<NCHUNKS, 256, 0, stream>>>(deg, chunkSums);
    k_scan23<<<NCHUNKS, 256, 0, stream>>>(deg, chunkSums, offs);
    k_fill<<<(N_EDGES + 255) / 256, 256, 0, stream>>>(src, dst, offs, rank, srcSorted);
    k_prep<<<(X2BF_ITEMS + 6 * 2048 + 255) / 256, 256, 0, stream>>>(x, W1s, W2s, Xbf, Wp);

    // layer 0: Xbf -> HA ; layer 1: HA -> HB ; layer 2: HB -> HA
    const unsigned short* in0 = Xbf;
    unsigned short* outs[3] = { HA, HB, HA };
    for (int l = 0; l < 3; l++) {
        const unsigned short* xin = (l == 0) ? in0 : outs[l - 1];
        if (l == 0)
            k_aggmlp<false><<<MLP_BLOCKS, 256, 0, stream>>>(
                xin, nullptr, offs, srcSorted,
                Wp + (size_t)(l * 2 + 0) * 16384, b1s + (size_t)l * HID,
                Wp + (size_t)(l * 2 + 1) * 16384, b2s + (size_t)l * HID, outs[l], bnpart);
        else
            k_aggmlp<true><<<MLP_BLOCKS, 256, 0, stream>>>(
                xin, bnsc, offs, srcSorted,
                Wp + (size_t)(l * 2 + 0) * 16384, b1s + (size_t)l * HID,
                Wp + (size_t)(l * 2 + 1) * 16384, b2s + (size_t)l * HID, outs[l], bnpart);
        k_bnred<<<64, 256, 0, stream>>>(bnpart, bnred2);
        k_bnscale<<<1, 256, 0, stream>>>(bnred2, gammas + (size_t)l * HID,
                                         betas + (size_t)l * HID, bnsc);
    }

    k_pool<<<(N_NODES + POOL_CHUNK - 1) / POOL_CHUNK, 256, 0, stream>>>(outs[2], bnsc, batch, g);
    k_final<<<(N_GRAPHS * OUTC + 255) / 256, 256, 0, stream>>>(g, Wlin, blin, out);
}